// Round 10
// baseline (151.512 us; speedup 1.0000x reference)
//
#include <hip/hip_runtime.h>

#define NN 40000      // nodes
#define NE 400000     // edges (before self loops)
#define NF 16         // in features
#define NH 8          // heads
#define NR 40         // routes
#define NK 39         // min(R1,R2)-1 logits kept
#define NEG 0.2f      // leaky relu slope
#define NBLK 157      // (NN+255)/256
#define NCH 16        // chunks per route
#define NB 157        // coarse buckets per graph (dst>>8)
#define SLOT 3328     // entries per bucket slot (mean 2560, +15 sigma)
#define BPG 391       // (NE+1023)/1024 blocks per graph
#define GAB 40        // (NN+1023)/1024 blocks per graph for k_a path

// float region offsets
#define OFF_AS   0                        // [2][NN*NH]
#define OFF_AD   (OFF_AS + 2*NN*NH)       // [2][NN*NH]
#define OFF_P    (OFF_AD + 2*NN*NH)       // [2][NR*NK]
#define OFF_PART (OFF_P + 2*NR*NK)        // [2][NR][NCH][128]
#define OFF_S    (OFF_PART + 2*NR*NCH*128)// [2][NN*64] uints (2 bf16 each)
#define OFF_INT  (OFF_S + 2*NN*64)
// int region (relative to OFF_INT) -- first three zeroed together (474 ints)
#define IOFF_RHIST  0                       // 2*NR
#define IOFF_BCUR   (2*NR)                  // 2*NB
#define IOFF_RCUR   (2*NR + 2*NB)           // 2*NR
#define IOFF_START  (IOFF_RCUR + 2*NR)      // 2*NN (absolute into srcs)
#define IOFF_DEG    (IOFF_START + 2*NN)     // 2*NN
#define IOFF_NID    (IOFF_DEG + 2*NN)       // 2*NN
#define IOFF_BINNED (IOFF_NID + 2*NN)       // 2*NB*SLOT
#define IOFF_SRC    (IOFF_BINNED + 2*NB*SLOT) // 2*NB*SLOT

static __device__ __forceinline__ unsigned int f2bf(float v) {
    unsigned int x = __float_as_uint(v);
    return (x + 0x7FFFu + ((x >> 16) & 1u)) >> 16;   // round-nearest-even
}
static __device__ __forceinline__ float bf2f(unsigned int u) {
    return __uint_as_float(u << 16);
}

// zero the atomic-counter arrays (rhist + bcur + rcur: 474 ints)
__global__ __launch_bounds__(512) void k_zero(int* __restrict__ p) {
    int i = threadIdx.x;
    if (i < 2 * NR + 2 * NB + 2 * NR) p[i] = 0;
}

// fused front: blocks [0,2*GAB) = per-node a_s/a_d + route hist;
//              blocks [2*GAB, ...) = edge coarse-binning
__global__ __launch_bounds__(1024) void k_front(const float* __restrict__ x1,
                                                const float* __restrict__ x2,
                                                const int* __restrict__ rv1,
                                                const int* __restrict__ rv2,
                                                const int* __restrict__ ei1,
                                                const int* __restrict__ ei2,
                                                const float* __restrict__ W,
                                                const float* __restrict__ asrc,
                                                const float* __restrict__ adst,
                                                float* __restrict__ as_,
                                                float* __restrict__ ad_,
                                                int* __restrict__ rhist,
                                                int* __restrict__ bcur,
                                                unsigned int* __restrict__ binned) {
    __shared__ float us[256];
    __shared__ int lh[NR];
    __shared__ int lhb[NB], lbb[NB];
    int tid = threadIdx.x;
    if (blockIdx.x < 2 * GAB) {
        // ---- k_a path: 1024 nodes per block ----
        if (tid < NR) lh[tid] = 0;
        if (tid < 256) {
            int tt = tid & 127;
            int f = tt >> 3, h = tt & 7;
            const float* av = (tid < 128 ? asrc : adst) + h * 64;
            const float* wrow = W + f * 512 + h * 64;
            float su = 0.f;
            for (int c = 0; c < 64; ++c) su += wrow[c] * av[c];
            us[tid] = su;  // [0:128)=u_src(f,h), [128:256)=u_dst(f,h)
        }
        __syncthreads();
        int g = blockIdx.x / GAB;
        int n = (blockIdx.x - g * GAB) * 1024 + tid;
        if (n < NN) {
            const float* x = g ? x2 : x1;
            const int* rv = g ? rv2 : rv1;
            const float4* xp = (const float4*)(x + n * NF);
            float4 v0 = xp[0], v1 = xp[1], v2 = xp[2], v3 = xp[3];
            float xv[16] = {v0.x, v0.y, v0.z, v0.w, v1.x, v1.y, v1.z, v1.w,
                            v2.x, v2.y, v2.z, v2.w, v3.x, v3.y, v3.z, v3.w};
            int o = g * NN * NH + n * NH;
            for (int h = 0; h < NH; ++h) {
                float s1 = 0.f, s2 = 0.f;
                for (int f = 0; f < NF; ++f) {
                    s1 += xv[f] * us[f * 8 + h];
                    s2 += xv[f] * us[128 + f * 8 + h];
                }
                as_[o + h] = s1;
                ad_[o + h] = s2;
            }
            atomicAdd(&lh[rv[n]], 1);
        }
        __syncthreads();
        if (tid < NR && lh[tid]) atomicAdd(&rhist[g * NR + tid], lh[tid]);
    } else {
        // ---- k_bin path ----
        int bid = blockIdx.x - 2 * GAB;
        int g = bid >= BPG;
        int blk = bid - g * BPG;
        if (tid < NB) lhb[tid] = 0;
        __syncthreads();
        int e = blk * 1024 + tid;
        const int* ei = g ? ei2 : ei1;
        unsigned int v = 0;
        int bin = 0, lpos = 0;
        bool valid = (e < NE);
        if (valid) {
            unsigned int s = (unsigned int)ei[e];
            unsigned int dv = (unsigned int)ei[NE + e];
            v = (dv << 16) | s;
            bin = dv >> 8;
            lpos = atomicAdd(&lhb[bin], 1);
        }
        __syncthreads();
        if (tid < NB && lhb[tid]) lbb[tid] = atomicAdd(&bcur[g * NB + tid], lhb[tid]);
        __syncthreads();
        if (valid) {
            int p = lbb[bin] + lpos;
            if (p < SLOT)
                __builtin_nontemporal_store(v, &binned[(g * NB + bin) * SLOT + p]);
        }
    }
}

// fused mid: blocks [0,2*NB) = per-bucket fine sort -> srcs/start/deg;
//            blocks [2*NB, ...) = route counting-sort of node ids
__global__ __launch_bounds__(256) void k_mid(const int* __restrict__ bcur,
                                             const unsigned int* __restrict__ binned,
                                             const int* __restrict__ rv1,
                                             const int* __restrict__ rv2,
                                             const int* __restrict__ rhist,
                                             int* __restrict__ rcur,
                                             int* __restrict__ start,
                                             int* __restrict__ deg,
                                             int* __restrict__ srcs,
                                             int* __restrict__ nid) {
    __shared__ unsigned int ed[SLOT];
    __shared__ int hist[256], scn[256];
    __shared__ int lh[NR], lbase[NR], rbase[NR];
    int tid = threadIdx.x;
    if (blockIdx.x < 2 * NB) {
        // ---- fine-sort path ----
        int gb = blockIdx.x;
        int g = gb >= NB;
        int b = gb - g * NB;
        int m = bcur[gb]; if (m > SLOT) m = SLOT;
        int base = gb * SLOT;
        for (int i = tid; i < m; i += 256) ed[i] = __builtin_nontemporal_load(&binned[base + i]);
        hist[tid] = 0;
        __syncthreads();
        for (int i = tid; i < m; i += 256) atomicAdd(&hist[(ed[i] >> 16) & 255], 1);
        __syncthreads();
        int v = hist[tid];
        scn[tid] = v;
        __syncthreads();
        for (int off = 1; off < 256; off <<= 1) {
            int u = (tid >= off) ? scn[tid - off] : 0;
            __syncthreads();
            scn[tid] += u;
            __syncthreads();
        }
        int excl = scn[tid] - v;
        int d = b * 256 + tid;
        if (d < NN) { start[g * NN + d] = base + excl; deg[g * NN + d] = v; }
        hist[tid] = excl;              // reuse as cursor
        __syncthreads();
        for (int i = tid; i < m; i += 256) {
            unsigned int e = ed[i];
            int ld = (e >> 16) & 255;
            int pos = atomicAdd(&hist[ld], 1);
            srcs[base + pos] = (int)(e & 0xffffu);
        }
    } else {
        // ---- node route-sort path ----
        int bid = blockIdx.x - 2 * NB;
        int g = bid / NBLK;
        int n = (bid - g * NBLK) * 256 + tid;
        const int* rv = g ? rv2 : rv1;
        if (tid < NR) lh[tid] = 0;
        __syncthreads();
        int r = 0, lpos = 0;
        bool valid = (n < NN);
        if (valid) { r = rv[n]; lpos = atomicAdd(&lh[r], 1); }
        if (tid == 0) {
            int run = 0;
            for (int rr = 0; rr < NR; ++rr) { rbase[rr] = run; run += rhist[g * NR + rr]; }
        }
        __syncthreads();
        if (tid < NR && lh[tid])
            lbase[tid] = rbase[tid] + atomicAdd(&rcur[g * NR + tid], lh[tid]);
        __syncthreads();
        if (valid) nid[g * NN + lbase[r] + lpos] = n;
    }
}

// gather: per dst a 64-lane wave, lane = (h, q). shfl redistribution as R9,
// but software-pipelined 2-deep over FULL batches (only tail is masked):
// both batches' srcs/as_/x loads are in flight together -> 2x MLP.
__global__ __launch_bounds__(256) void k_gather(const int* __restrict__ start,
                                                const int* __restrict__ deg,
                                                const int* __restrict__ srcs,
                                                const float* __restrict__ as_,
                                                const float* __restrict__ ad_,
                                                const float* __restrict__ x1,
                                                const float* __restrict__ x2,
                                                unsigned int* __restrict__ sb) {
    int idx = blockIdx.x * 4 + (threadIdx.x >> 6);   // 0..2*NN-1
    int g = idx >= NN;
    int d = idx - g * NN;
    const float* x = g ? x2 : x1;
    const float* asg = as_ + (size_t)g * NN * NH;
    int lane = threadIdx.x & 63;
    int h = lane >> 3, q = lane & 7;
    float adv = ad_[(size_t)g * NN * NH + d * NH + h];
    // self loop
    float e0 = asg[d * NH + h] + adv;
    e0 = (e0 > 0.f) ? e0 : NEG * e0;
    float w0 = __expf(e0);
    float2 xv = *(const float2*)(x + d * NF + q * 2);
    float wsum = w0;
    float ax = w0 * xv.x, ay = w0 * xv.y;
    int base = __builtin_amdgcn_readfirstlane(start[idx]);
    int dg   = __builtin_amdgcn_readfirstlane(deg[idx]);
    int nfull = dg >> 3;
    int b = 0;
    // ---- pipelined pairs of FULL batches (no masking) ----
    for (; b + 1 < nfull; b += 2) {
        int offA = base + b * 8, offB = offA + 8;
        int sqA = srcs[offA + q];
        int sqB = srcs[offB + q];
        float evA = asg[sqA * NH + h] + adv;
        float evB = asg[sqB * NH + h] + adv;
        evA = (evA > 0.f) ? evA : NEG * evA;
        evB = (evB > 0.f) ? evB : NEG * evB;
        float wA = __expf(evA), wB = __expf(evB);
        int sBA = __shfl(sqA, lane >> 3);
        int sBB = __shfl(sqB, lane >> 3);
        float2 xrA = *(const float2*)(x + sBA * NF + q * 2);
        float2 xrB = *(const float2*)(x + sBB * NF + q * 2);
        #pragma unroll
        for (int j = 0; j < 8; ++j) {
            float wj  = __shfl(wA,    (lane & 56) | j);
            float xjx = __shfl(xrA.x, (j << 3) | q);
            float xjy = __shfl(xrA.y, (j << 3) | q);
            wsum += wj; ax += wj * xjx; ay += wj * xjy;
        }
        #pragma unroll
        for (int j = 0; j < 8; ++j) {
            float wj  = __shfl(wB,    (lane & 56) | j);
            float xjx = __shfl(xrB.x, (j << 3) | q);
            float xjy = __shfl(xrB.y, (j << 3) | q);
            wsum += wj; ax += wj * xjx; ay += wj * xjy;
        }
    }
    // ---- remaining single full batch ----
    for (; b < nfull; ++b) {
        int off = base + b * 8;
        int sq = srcs[off + q];
        float ev = asg[sq * NH + h] + adv;
        ev = (ev > 0.f) ? ev : NEG * ev;
        float wq = __expf(ev);
        int sB = __shfl(sq, lane >> 3);
        float2 xr = *(const float2*)(x + sB * NF + q * 2);
        #pragma unroll
        for (int j = 0; j < 8; ++j) {
            float wj  = __shfl(wq,   (lane & 56) | j);
            float xjx = __shfl(xr.x, (j << 3) | q);
            float xjy = __shfl(xr.y, (j << 3) | q);
            wsum += wj; ax += wj * xjx; ay += wj * xjy;
        }
    }
    // ---- masked tail (rem edges) ----
    int rem = dg & 7;
    if (rem) {
        int off = base + nfull * 8;
        int aq = (q < rem) ? off + q : base;   // clamp (dg>0 here)
        int sq = srcs[aq];
        float ev = asg[sq * NH + h] + adv;
        ev = (ev > 0.f) ? ev : NEG * ev;
        float wq = (q < rem) ? __expf(ev) : 0.f;
        int sB = __shfl(sq, lane >> 3);
        float2 xr = *(const float2*)(x + sB * NF + q * 2);
        #pragma unroll
        for (int j = 0; j < 8; ++j) {
            float wj  = __shfl(wq,   (lane & 56) | j);
            float xjx = __shfl(xr.x, (j << 3) | q);
            float xjy = __shfl(xr.y, (j << 3) | q);
            wsum += wj; ax += wj * xjx; ay += wj * xjy;
        }
    }
    float inv = 1.0f / wsum;
    unsigned int pk = (f2bf(ay * inv) << 16) | f2bf(ax * inv);
    __builtin_nontemporal_store(pk, &sb[(size_t)idx * 64 + lane]);
}

// route-sorted register accumulation: block = (g,r,chunk), rstart from rhist
__global__ __launch_bounds__(256) void k_rnode(const int* __restrict__ rhist,
                                               const int* __restrict__ nid,
                                               const unsigned int* __restrict__ sb,
                                               float* __restrict__ part) {
    __shared__ float red[4][128];
    __shared__ int sseg[2];
    int g = blockIdx.x >= NR * NCH;
    int bid = blockIdx.x - g * NR * NCH;
    int r = bid / NCH, ch = bid - r * NCH;
    if (threadIdx.x == 0) {
        int acc = 0;
        for (int rr = 0; rr < r; ++rr) acc += rhist[g * NR + rr];
        sseg[0] = acc;
        sseg[1] = rhist[g * NR + r];
    }
    __syncthreads();
    int seg0 = sseg[0], dgr = sseg[1];
    int csz = (dgr + NCH - 1) / NCH;
    int a = seg0 + ch * csz;
    int b = seg0 + dgr; { int bb = a + csz; if (bb < b) b = bb; }
    int ln = threadIdx.x >> 6, c = threadIdx.x & 63;
    const int* np = nid + g * NN;
    const unsigned int* sg = sb + (size_t)g * NN * 64;
    float sx = 0.f, sy = 0.f;
    for (int i = a + ln; i < b; i += 4) {
        int n = np[i];
        unsigned int pk = __builtin_nontemporal_load(&sg[(size_t)n * 64 + c]);
        sx += bf2f(pk & 0xffffu);
        sy += bf2f(pk >> 16);
    }
    red[ln][c * 2] = sx;
    red[ln][c * 2 + 1] = sy;
    __syncthreads();
    int tid = threadIdx.x;
    if (tid < 128) {
        float s = red[0][tid] + red[1][tid] + red[2][tid] + red[3][tid];
        part[((g * NR + r) * NCH + ch) * 128 + tid] = s;
    }
}

// fused: chunk-partial reduce -> t row -> agg row (512) -> P[g,i,k]
__global__ __launch_bounds__(256) void k_head(const float* __restrict__ part,
                                              const int* __restrict__ rhist,
                                              const float* __restrict__ W,
                                              const float* __restrict__ bias,
                                              const float* __restrict__ Wh,
                                              float* __restrict__ P) {
    __shared__ float trow[128];
    __shared__ float aggL[512];
    __shared__ float scnt;
    int g = blockIdx.x / NR, i = blockIdx.x - g * NR;
    int tid = threadIdx.x;
    if (tid < 128) {
        const float* pp = part + ((g * NR + i) * NCH) * 128 + tid;
        float s = 0.f;
        for (int ch = 0; ch < NCH; ++ch) s += pp[ch * 128];
        trow[tid] = s;
    }
    if (tid == 0) scnt = (float)rhist[g * NR + i];
    __syncthreads();
    for (int hc = tid; hc < 512; hc += 256) {
        int h = hc >> 6;
        float acc = scnt * bias[hc];
        const float* tp = trow + h * 16;
        for (int f = 0; f < 16; ++f) acc += tp[f] * W[f * 512 + hc];
        aggL[hc] = acc;
    }
    __syncthreads();
    if (tid < 4 * NK) {
        int k = tid >> 2, qq = tid & 3;
        const float* wp = Wh + (size_t)(g * 512 + qq * 128) * 61 + k;
        const float* ap = aggL + qq * 128;
        float acc = 0.f;
        for (int d = 0; d < 128; ++d) acc += ap[d] * wp[d * 61];
        acc += __shfl_down(acc, 1);
        acc += __shfl_down(acc, 2);
        if (qq == 0) P[(g * NR + i) * NK + k] = acc;
    }
}

// logits[i,j,k] = P1[i,k]+P2[j,k]+b[k]; global softmax over 62400
__global__ __launch_bounds__(1024) void k_final(const float* __restrict__ P,
                                                const float* __restrict__ bh,
                                                float* __restrict__ out) {
    __shared__ float p1[NR * NK], p2[NR * NK], bsh[NK];
    __shared__ float red[16];
    __shared__ float bc[2];
    int tid = threadIdx.x;
    for (int i = tid; i < NR * NK; i += 1024) { p1[i] = P[i]; p2[i] = P[NR * NK + i]; }
    if (tid < NK) bsh[tid] = bh[tid];
    __syncthreads();
    const int TOT = NR * NR * NK;
    float m = -3.0e38f;
    for (int idx = tid; idx < TOT; idx += 1024) {
        int i = idx / (NR * NK);
        int r = idx - i * (NR * NK);
        int j = r / NK;
        int k = r - j * NK;
        float l = p1[i * NK + k] + p2[j * NK + k] + bsh[k];
        m = fmaxf(m, l);
    }
    for (int off = 32; off > 0; off >>= 1) m = fmaxf(m, __shfl_down(m, off));
    if ((tid & 63) == 0) red[tid >> 6] = m;
    __syncthreads();
    if (tid == 0) {
        float g = red[0];
        for (int w = 1; w < 16; ++w) g = fmaxf(g, red[w]);
        bc[0] = g;
    }
    __syncthreads();
    float gm = bc[0];
    __syncthreads();
    float sum = 0.f;
    for (int idx = tid; idx < TOT; idx += 1024) {
        int i = idx / (NR * NK);
        int r = idx - i * (NR * NK);
        int j = r / NK;
        int k = r - j * NK;
        float l = p1[i * NK + k] + p2[j * NK + k] + bsh[k];
        sum += __expf(l - gm);
    }
    for (int off = 32; off > 0; off >>= 1) sum += __shfl_down(sum, off);
    if ((tid & 63) == 0) red[tid >> 6] = sum;
    __syncthreads();
    if (tid == 0) {
        float g = 0.f;
        for (int w = 0; w < 16; ++w) g += red[w];
        bc[1] = 1.0f / g;
    }
    __syncthreads();
    float inv = bc[1];
    for (int idx = tid; idx < TOT; idx += 1024) {
        int i = idx / (NR * NK);
        int r = idx - i * (NR * NK);
        int j = r / NK;
        int k = r - j * NK;
        float l = p1[i * NK + k] + p2[j * NK + k] + bsh[k];
        out[idx] = __expf(l - gm) * inv;
    }
}

extern "C" void kernel_launch(void* const* d_in, const int* in_sizes, int n_in,
                              void* d_out, int out_size, void* d_ws, size_t ws_size,
                              hipStream_t stream) {
    const float* x1   = (const float*)d_in[0];
    const int*   ei1  = (const int*)d_in[1];
    const int*   rv1  = (const int*)d_in[3];
    const float* x2   = (const float*)d_in[5];
    const int*   ei2  = (const int*)d_in[6];
    const int*   rv2  = (const int*)d_in[8];
    const float* Wg   = (const float*)d_in[10];
    const float* asrc = (const float*)d_in[11];
    const float* adst = (const float*)d_in[12];
    const float* bias = (const float*)d_in[13];
    const float* Wh   = (const float*)d_in[14];
    const float* bh   = (const float*)d_in[15];
    float* out = (float*)d_out;
    float* ws  = (float*)d_ws;

    float* as_  = ws + OFF_AS;
    float* ad_  = ws + OFF_AD;
    float* P    = ws + OFF_P;
    float* part = ws + OFF_PART;
    unsigned int* sb = (unsigned int*)(ws + OFF_S);
    int* ibase  = (int*)(ws + OFF_INT);
    int* rhist  = ibase + IOFF_RHIST;
    int* bcur   = ibase + IOFF_BCUR;
    int* rcur   = ibase + IOFF_RCUR;
    int* start  = ibase + IOFF_START;
    int* deg    = ibase + IOFF_DEG;
    int* nid    = ibase + IOFF_NID;
    unsigned int* binned = (unsigned int*)(ibase + IOFF_BINNED);
    int* srcs   = ibase + IOFF_SRC;

    k_zero<<<1, 512, 0, stream>>>(rhist);
    k_front<<<2 * GAB + 2 * BPG, 1024, 0, stream>>>(x1, x2, rv1, rv2, ei1, ei2,
                                                    Wg, asrc, adst, as_, ad_,
                                                    rhist, bcur, binned);
    k_mid<<<2 * NB + 2 * NBLK, 256, 0, stream>>>(bcur, binned, rv1, rv2, rhist,
                                                 rcur, start, deg, srcs, nid);
    k_gather<<<2 * NN / 4, 256, 0, stream>>>(start, deg, srcs, as_, ad_, x1, x2, sb);
    k_rnode<<<2 * NR * NCH, 256, 0, stream>>>(rhist, nid, sb, part);
    k_head<<<2 * NR, 256, 0, stream>>>(part, rhist, Wg, bias, Wh, P);
    k_final<<<1, 1024, 0, stream>>>(P, bh, out);
}

// Round 11
// 120.251 us; speedup vs baseline: 1.2600x; 1.2600x over previous
//
#include <hip/hip_runtime.h>

#define NN 40000      // nodes
#define NE 400000     // edges (before self loops)
#define NF 16         // in features
#define NH 8          // heads
#define NR 40         // routes
#define NK 39         // min(R1,R2)-1 logits kept
#define NEG 0.2f      // leaky relu slope
#define NBLK 157      // (NN+255)/256
#define NCH 16        // chunks per route
#define NB 157        // coarse buckets per graph (dst>>8)
#define SLOT 3328     // entries per bucket slot (mean 2560, +15 sigma)
#define BPG 391       // (NE+1023)/1024 blocks per graph
#define GAB 40        // (NN+1023)/1024 blocks per graph for k_a path

// float region offsets
#define OFF_AS   0                        // [2][NN*NH]
#define OFF_AD   (OFF_AS + 2*NN*NH)       // [2][NN*NH]
#define OFF_P    (OFF_AD + 2*NN*NH)       // [2][NR*NK]
#define OFF_PART (OFF_P + 2*NR*NK)        // [2][NR][NCH][128]
#define OFF_S    (OFF_PART + 2*NR*NCH*128)// [2][NN*64] uints (2 bf16 each)
#define OFF_INT  (OFF_S + 2*NN*64)
// int region (relative to OFF_INT) -- first three zeroed together (474 ints)
#define IOFF_RHIST  0                       // 2*NR
#define IOFF_BCUR   (2*NR)                  // 2*NB
#define IOFF_RCUR   (2*NR + 2*NB)           // 2*NR
#define IOFF_START  (IOFF_RCUR + 2*NR)      // 2*NN (absolute into srcs)
#define IOFF_DEG    (IOFF_START + 2*NN)     // 2*NN
#define IOFF_NID    (IOFF_DEG + 2*NN)       // 2*NN
#define IOFF_BINNED (IOFF_NID + 2*NN)       // 2*NB*SLOT
#define IOFF_SRC    (IOFF_BINNED + 2*NB*SLOT) // 2*NB*SLOT + 1 (sentinel)

static __device__ __forceinline__ unsigned int f2bf(float v) {
    unsigned int x = __float_as_uint(v);
    return (x + 0x7FFFu + ((x >> 16) & 1u)) >> 16;   // round-nearest-even
}
static __device__ __forceinline__ float bf2f(unsigned int u) {
    return __uint_as_float(u << 16);
}

// zero the atomic-counter arrays + write srcs end-sentinel
__global__ __launch_bounds__(512) void k_zero(int* __restrict__ p,
                                              int* __restrict__ srcs) {
    int i = threadIdx.x;
    if (i < 2 * NR + 2 * NB + 2 * NR) p[i] = 0;
    if (i == 0) srcs[2 * NB * SLOT] = 0;   // clamped reads of 0-deg dsts land here
}

// fused front: blocks [0,2*GAB) = per-node a_s/a_d + route hist;
//              blocks [2*GAB, ...) = edge coarse-binning
__global__ __launch_bounds__(1024) void k_front(const float* __restrict__ x1,
                                                const float* __restrict__ x2,
                                                const int* __restrict__ rv1,
                                                const int* __restrict__ rv2,
                                                const int* __restrict__ ei1,
                                                const int* __restrict__ ei2,
                                                const float* __restrict__ W,
                                                const float* __restrict__ asrc,
                                                const float* __restrict__ adst,
                                                float* __restrict__ as_,
                                                float* __restrict__ ad_,
                                                int* __restrict__ rhist,
                                                int* __restrict__ bcur,
                                                unsigned int* __restrict__ binned) {
    __shared__ float us[256];
    __shared__ int lh[NR];
    __shared__ int lhb[NB], lbb[NB];
    int tid = threadIdx.x;
    if (blockIdx.x < 2 * GAB) {
        // ---- k_a path: 1024 nodes per block ----
        if (tid < NR) lh[tid] = 0;
        if (tid < 256) {
            int tt = tid & 127;
            int f = tt >> 3, h = tt & 7;
            const float* av = (tid < 128 ? asrc : adst) + h * 64;
            const float* wrow = W + f * 512 + h * 64;
            float su = 0.f;
            for (int c = 0; c < 64; ++c) su += wrow[c] * av[c];
            us[tid] = su;  // [0:128)=u_src(f,h), [128:256)=u_dst(f,h)
        }
        __syncthreads();
        int g = blockIdx.x / GAB;
        int n = (blockIdx.x - g * GAB) * 1024 + tid;
        if (n < NN) {
            const float* x = g ? x2 : x1;
            const int* rv = g ? rv2 : rv1;
            const float4* xp = (const float4*)(x + n * NF);
            float4 v0 = xp[0], v1 = xp[1], v2 = xp[2], v3 = xp[3];
            float xv[16] = {v0.x, v0.y, v0.z, v0.w, v1.x, v1.y, v1.z, v1.w,
                            v2.x, v2.y, v2.z, v2.w, v3.x, v3.y, v3.z, v3.w};
            int o = g * NN * NH + n * NH;
            for (int h = 0; h < NH; ++h) {
                float s1 = 0.f, s2 = 0.f;
                for (int f = 0; f < NF; ++f) {
                    s1 += xv[f] * us[f * 8 + h];
                    s2 += xv[f] * us[128 + f * 8 + h];
                }
                as_[o + h] = s1;
                ad_[o + h] = s2;
            }
            atomicAdd(&lh[rv[n]], 1);
        }
        __syncthreads();
        if (tid < NR && lh[tid]) atomicAdd(&rhist[g * NR + tid], lh[tid]);
    } else {
        // ---- k_bin path ----
        int bid = blockIdx.x - 2 * GAB;
        int g = bid >= BPG;
        int blk = bid - g * BPG;
        if (tid < NB) lhb[tid] = 0;
        __syncthreads();
        int e = blk * 1024 + tid;
        const int* ei = g ? ei2 : ei1;
        unsigned int v = 0;
        int bin = 0, lpos = 0;
        bool valid = (e < NE);
        if (valid) {
            unsigned int s = (unsigned int)ei[e];
            unsigned int dv = (unsigned int)ei[NE + e];
            v = (dv << 16) | s;
            bin = dv >> 8;
            lpos = atomicAdd(&lhb[bin], 1);
        }
        __syncthreads();
        if (tid < NB && lhb[tid]) lbb[tid] = atomicAdd(&bcur[g * NB + tid], lhb[tid]);
        __syncthreads();
        if (valid) {
            int p = lbb[bin] + lpos;
            if (p < SLOT) binned[(g * NB + bin) * SLOT + p] = v;
        }
    }
}

// fused mid: blocks [0,2*NB) = per-bucket fine sort -> srcs/start/deg;
//            blocks [2*NB, ...) = route counting-sort of node ids
__global__ __launch_bounds__(256) void k_mid(const int* __restrict__ bcur,
                                             const unsigned int* __restrict__ binned,
                                             const int* __restrict__ rv1,
                                             const int* __restrict__ rv2,
                                             const int* __restrict__ rhist,
                                             int* __restrict__ rcur,
                                             int* __restrict__ start,
                                             int* __restrict__ deg,
                                             int* __restrict__ srcs,
                                             int* __restrict__ nid) {
    __shared__ unsigned int ed[SLOT];
    __shared__ int hist[256], scn[256];
    __shared__ int lh[NR], lbase[NR], rbase[NR];
    int tid = threadIdx.x;
    if (blockIdx.x < 2 * NB) {
        // ---- fine-sort path ----
        int gb = blockIdx.x;
        int g = gb >= NB;
        int b = gb - g * NB;
        int m = bcur[gb]; if (m > SLOT) m = SLOT;
        int base = gb * SLOT;
        for (int i = tid; i < m; i += 256) ed[i] = binned[base + i];
        hist[tid] = 0;
        __syncthreads();
        for (int i = tid; i < m; i += 256) atomicAdd(&hist[(ed[i] >> 16) & 255], 1);
        __syncthreads();
        int v = hist[tid];
        scn[tid] = v;
        __syncthreads();
        for (int off = 1; off < 256; off <<= 1) {
            int u = (tid >= off) ? scn[tid - off] : 0;
            __syncthreads();
            scn[tid] += u;
            __syncthreads();
        }
        int excl = scn[tid] - v;
        int d = b * 256 + tid;
        if (d < NN) { start[g * NN + d] = base + excl; deg[g * NN + d] = v; }
        hist[tid] = excl;              // reuse as cursor
        __syncthreads();
        for (int i = tid; i < m; i += 256) {
            unsigned int e = ed[i];
            int ld = (e >> 16) & 255;
            int pos = atomicAdd(&hist[ld], 1);
            srcs[base + pos] = (int)(e & 0xffffu);
        }
    } else {
        // ---- node route-sort path ----
        int bid = blockIdx.x - 2 * NB;
        int g = bid / NBLK;
        int n = (bid - g * NBLK) * 256 + tid;
        const int* rv = g ? rv2 : rv1;
        if (tid < NR) lh[tid] = 0;
        __syncthreads();
        int r = 0, lpos = 0;
        bool valid = (n < NN);
        if (valid) { r = rv[n]; lpos = atomicAdd(&lh[r], 1); }
        if (tid == 0) {
            int run = 0;
            for (int rr = 0; rr < NR; ++rr) { rbase[rr] = run; run += rhist[g * NR + rr]; }
        }
        __syncthreads();
        if (tid < NR && lh[tid])
            lbase[tid] = rbase[tid] + atomicAdd(&rcur[g * NR + tid], lh[tid]);
        __syncthreads();
        if (valid) nid[g * NN + lbase[r] + lpos] = n;
    }
}

// gather: one wave per PAIR of adjacent dsts (cross-dst ILP: both dsts'
// srcs/as_/x chains in flight every iteration). lane = (h, q); shfl
// redistribution as R9; masked batches cover deg mismatch; srcs end-sentinel
// makes clamped reads of 0-deg dsts safe.
__global__ __launch_bounds__(256) void k_gather(const int* __restrict__ start,
                                                const int* __restrict__ deg,
                                                const int* __restrict__ srcs,
                                                const float* __restrict__ as_,
                                                const float* __restrict__ ad_,
                                                const float* __restrict__ x1,
                                                const float* __restrict__ x2,
                                                unsigned int* __restrict__ sb) {
    int wid = blockIdx.x * 4 + (threadIdx.x >> 6);   // 0..NN-1 (pairs)
    int idx0 = wid * 2, idx1 = idx0 + 1;             // never straddles graphs
    int g = idx0 >= NN;
    int d0 = idx0 - g * NN, d1 = d0 + 1;
    const float* x = g ? x2 : x1;
    const float* asg = as_ + (size_t)g * NN * NH;
    const float* adg = ad_ + (size_t)g * NN * NH;
    int lane = threadIdx.x & 63;
    int h = lane >> 3, q = lane & 7;
    // issue both dsts' setup loads together
    int base0 = __builtin_amdgcn_readfirstlane(start[idx0]);
    int dg0   = __builtin_amdgcn_readfirstlane(deg[idx0]);
    int base1 = __builtin_amdgcn_readfirstlane(start[idx1]);
    int dg1   = __builtin_amdgcn_readfirstlane(deg[idx1]);
    float adv0 = adg[d0 * NH + h];
    float adv1 = adg[d1 * NH + h];
    float as0 = asg[d0 * NH + h];
    float as1 = asg[d1 * NH + h];
    float2 xv0 = *(const float2*)(x + d0 * NF + q * 2);
    float2 xv1 = *(const float2*)(x + d1 * NF + q * 2);
    float e00 = as0 + adv0; e00 = (e00 > 0.f) ? e00 : NEG * e00;
    float e01 = as1 + adv1; e01 = (e01 > 0.f) ? e01 : NEG * e01;
    float w00 = __expf(e00), w01 = __expf(e01);
    float ws0 = w00, ax0 = w00 * xv0.x, ay0 = w00 * xv0.y;
    float ws1 = w01, ax1 = w01 * xv1.x, ay1 = w01 * xv1.y;
    int nb0 = (dg0 + 7) >> 3, nb1 = (dg1 + 7) >> 3;
    int nb = (nb0 > nb1) ? nb0 : nb1;
    for (int b = 0; b < nb; ++b) {
        int lim0 = dg0 - b * 8;               // may be <=0 (masked out)
        int lim1 = dg1 - b * 8;
        int aq0 = (q < lim0) ? base0 + b * 8 + q : base0;
        int aq1 = (q < lim1) ? base1 + b * 8 + q : base1;
        int sq0 = srcs[aq0];                  // both loads in flight
        int sq1 = srcs[aq1];
        float ev0 = asg[sq0 * NH + h] + adv0;
        float ev1 = asg[sq1 * NH + h] + adv1;
        ev0 = (ev0 > 0.f) ? ev0 : NEG * ev0;
        ev1 = (ev1 > 0.f) ? ev1 : NEG * ev1;
        float wq0 = (q < lim0) ? __expf(ev0) : 0.f;
        float wq1 = (q < lim1) ? __expf(ev1) : 0.f;
        int sB0 = __shfl(sq0, lane >> 3);
        int sB1 = __shfl(sq1, lane >> 3);
        float2 xr0 = *(const float2*)(x + sB0 * NF + q * 2);
        float2 xr1 = *(const float2*)(x + sB1 * NF + q * 2);
        #pragma unroll
        for (int j = 0; j < 8; ++j) {
            float wj0 = __shfl(wq0,   (lane & 56) | j);
            float wj1 = __shfl(wq1,   (lane & 56) | j);
            float xx0 = __shfl(xr0.x, (j << 3) | q);
            float xy0 = __shfl(xr0.y, (j << 3) | q);
            float xx1 = __shfl(xr1.x, (j << 3) | q);
            float xy1 = __shfl(xr1.y, (j << 3) | q);
            ws0 += wj0; ax0 += wj0 * xx0; ay0 += wj0 * xy0;
            ws1 += wj1; ax1 += wj1 * xx1; ay1 += wj1 * xy1;
        }
    }
    float inv0 = 1.0f / ws0, inv1 = 1.0f / ws1;
    unsigned int pk0 = (f2bf(ay0 * inv0) << 16) | f2bf(ax0 * inv0);
    unsigned int pk1 = (f2bf(ay1 * inv1) << 16) | f2bf(ax1 * inv1);
    sb[(size_t)idx0 * 64 + lane] = pk0;
    sb[(size_t)idx1 * 64 + lane] = pk1;
}

// route-sorted register accumulation: block = (g,r,chunk), rstart from rhist
__global__ __launch_bounds__(256) void k_rnode(const int* __restrict__ rhist,
                                               const int* __restrict__ nid,
                                               const unsigned int* __restrict__ sb,
                                               float* __restrict__ part) {
    __shared__ float red[4][128];
    __shared__ int sseg[2];
    int g = blockIdx.x >= NR * NCH;
    int bid = blockIdx.x - g * NR * NCH;
    int r = bid / NCH, ch = bid - r * NCH;
    if (threadIdx.x == 0) {
        int acc = 0;
        for (int rr = 0; rr < r; ++rr) acc += rhist[g * NR + rr];
        sseg[0] = acc;
        sseg[1] = rhist[g * NR + r];
    }
    __syncthreads();
    int seg0 = sseg[0], dgr = sseg[1];
    int csz = (dgr + NCH - 1) / NCH;
    int a = seg0 + ch * csz;
    int b = seg0 + dgr; { int bb = a + csz; if (bb < b) b = bb; }
    int ln = threadIdx.x >> 6, c = threadIdx.x & 63;
    const int* np = nid + g * NN;
    const unsigned int* sg = sb + (size_t)g * NN * 64;
    float sx = 0.f, sy = 0.f;
    for (int i = a + ln; i < b; i += 4) {
        int n = np[i];
        unsigned int pk = sg[(size_t)n * 64 + c];
        sx += bf2f(pk & 0xffffu);
        sy += bf2f(pk >> 16);
    }
    red[ln][c * 2] = sx;
    red[ln][c * 2 + 1] = sy;
    __syncthreads();
    int tid = threadIdx.x;
    if (tid < 128) {
        float s = red[0][tid] + red[1][tid] + red[2][tid] + red[3][tid];
        part[((g * NR + r) * NCH + ch) * 128 + tid] = s;
    }
}

// fused: chunk-partial reduce -> t row -> agg row (512) -> P[g,i,k]
__global__ __launch_bounds__(256) void k_head(const float* __restrict__ part,
                                              const int* __restrict__ rhist,
                                              const float* __restrict__ W,
                                              const float* __restrict__ bias,
                                              const float* __restrict__ Wh,
                                              float* __restrict__ P) {
    __shared__ float trow[128];
    __shared__ float aggL[512];
    __shared__ float scnt;
    int g = blockIdx.x / NR, i = blockIdx.x - g * NR;
    int tid = threadIdx.x;
    if (tid < 128) {
        const float* pp = part + ((g * NR + i) * NCH) * 128 + tid;
        float s = 0.f;
        for (int ch = 0; ch < NCH; ++ch) s += pp[ch * 128];
        trow[tid] = s;
    }
    if (tid == 0) scnt = (float)rhist[g * NR + i];
    __syncthreads();
    for (int hc = tid; hc < 512; hc += 256) {
        int h = hc >> 6;
        float acc = scnt * bias[hc];
        const float* tp = trow + h * 16;
        for (int f = 0; f < 16; ++f) acc += tp[f] * W[f * 512 + hc];
        aggL[hc] = acc;
    }
    __syncthreads();
    if (tid < 4 * NK) {
        int k = tid >> 2, qq = tid & 3;
        const float* wp = Wh + (size_t)(g * 512 + qq * 128) * 61 + k;
        const float* ap = aggL + qq * 128;
        float acc = 0.f;
        for (int d = 0; d < 128; ++d) acc += ap[d] * wp[d * 61];
        acc += __shfl_down(acc, 1);
        acc += __shfl_down(acc, 2);
        if (qq == 0) P[(g * NR + i) * NK + k] = acc;
    }
}

// factorized global softmax: logits = p1[i,k]+p2[j,k]+b[k]
//   max and denom factorize per-k; out = e1[i,k]*e2[j,k]*f[k]
__global__ __launch_bounds__(1024) void k_final(const float* __restrict__ P,
                                                const float* __restrict__ bh,
                                                float* __restrict__ out) {
    __shared__ float p1[NR * NK], p2[NR * NK];     // overwritten with e1,e2
    __shared__ float ak[NK], ck[NK], s1k[NK], s2k[NK];
    __shared__ float fk[NK];
    int tid = threadIdx.x;
    for (int i = tid; i < NR * NK; i += 1024) { p1[i] = P[i]; p2[i] = P[NR * NK + i]; }
    __syncthreads();
    if (tid < 2 * NK) {
        int k = (tid < NK) ? tid : tid - NK;
        float* pp = (tid < NK) ? p1 : p2;
        float a = -3.0e38f;
        for (int i = 0; i < NR; ++i) a = fmaxf(a, pp[i * NK + k]);
        float s = 0.f;
        for (int i = 0; i < NR; ++i) {
            float e = __expf(pp[i * NK + k] - a);
            pp[i * NK + k] = e;                    // p -> e in place
            s += e;
        }
        if (tid < NK) { ak[k] = a; s1k[k] = s; }
        else          { ck[k] = a; s2k[k] = s; }
    }
    __syncthreads();
    if (tid == 0) {
        float M = -3.0e38f;
        float mk[NK];
        for (int k = 0; k < NK; ++k) {
            mk[k] = ak[k] + ck[k] + bh[k];
            M = fmaxf(M, mk[k]);
        }
        float den = 0.f;
        for (int k = 0; k < NK; ++k) den += s1k[k] * s2k[k] * __expf(mk[k] - M);
        float invden = 1.0f / den;
        for (int k = 0; k < NK; ++k) fk[k] = __expf(mk[k] - M) * invden;
    }
    __syncthreads();
    const int TOT = NR * NR * NK;
    for (int idx = tid; idx < TOT; idx += 1024) {
        int i = idx / (NR * NK);
        int r = idx - i * (NR * NK);
        int j = r / NK;
        int k = r - j * NK;
        out[idx] = p1[i * NK + k] * p2[j * NK + k] * fk[k];
    }
}

extern "C" void kernel_launch(void* const* d_in, const int* in_sizes, int n_in,
                              void* d_out, int out_size, void* d_ws, size_t ws_size,
                              hipStream_t stream) {
    const float* x1   = (const float*)d_in[0];
    const int*   ei1  = (const int*)d_in[1];
    const int*   rv1  = (const int*)d_in[3];
    const float* x2   = (const float*)d_in[5];
    const int*   ei2  = (const int*)d_in[6];
    const int*   rv2  = (const int*)d_in[8];
    const float* Wg   = (const float*)d_in[10];
    const float* asrc = (const float*)d_in[11];
    const float* adst = (const float*)d_in[12];
    const float* bias = (const float*)d_in[13];
    const float* Wh   = (const float*)d_in[14];
    const float* bh   = (const float*)d_in[15];
    float* out = (float*)d_out;
    float* ws  = (float*)d_ws;

    float* as_  = ws + OFF_AS;
    float* ad_  = ws + OFF_AD;
    float* P    = ws + OFF_P;
    float* part = ws + OFF_PART;
    unsigned int* sb = (unsigned int*)(ws + OFF_S);
    int* ibase  = (int*)(ws + OFF_INT);
    int* rhist  = ibase + IOFF_RHIST;
    int* bcur   = ibase + IOFF_BCUR;
    int* rcur   = ibase + IOFF_RCUR;
    int* start  = ibase + IOFF_START;
    int* deg    = ibase + IOFF_DEG;
    int* nid    = ibase + IOFF_NID;
    unsigned int* binned = (unsigned int*)(ibase + IOFF_BINNED);
    int* srcs   = ibase + IOFF_SRC;

    k_zero<<<1, 512, 0, stream>>>(rhist, srcs);
    k_front<<<2 * GAB + 2 * BPG, 1024, 0, stream>>>(x1, x2, rv1, rv2, ei1, ei2,
                                                    Wg, asrc, adst, as_, ad_,
                                                    rhist, bcur, binned);
    k_mid<<<2 * NB + 2 * NBLK, 256, 0, stream>>>(bcur, binned, rv1, rv2, rhist,
                                                 rcur, start, deg, srcs, nid);
    k_gather<<<NN / 4, 256, 0, stream>>>(start, deg, srcs, as_, ad_, x1, x2, sb);
    k_rnode<<<2 * NR * NCH, 256, 0, stream>>>(rhist, nid, sb, part);
    k_head<<<2 * NR, 256, 0, stream>>>(part, rhist, Wg, bias, Wh, P);
    k_final<<<1, 1024, 0, stream>>>(P, bh, out);
}

// Round 12
// 119.621 us; speedup vs baseline: 1.2666x; 1.0053x over previous
//
#include <hip/hip_runtime.h>

#define NN 40000      // nodes
#define NE 400000     // edges (before self loops)
#define NF 16         // in features
#define NH 8          // heads
#define NR 40         // routes
#define NK 39         // min(R1,R2)-1 logits kept
#define NEG 0.2f      // leaky relu slope
#define NBLK 157      // (NN+255)/256
#define NCH 16        // chunks per route
#define NB 157        // coarse buckets per graph (dst>>8)
#define SLOT 3328     // entries per bucket slot (mean 2560, +15 sigma)
#define BPG 391       // (NE+1023)/1024 blocks per graph
#define GAB 40        // (NN+1023)/1024 blocks per graph for k_a path

// float region offsets
#define OFF_AS   0                        // [2][NN*NH]
#define OFF_AD   (OFF_AS + 2*NN*NH)       // [2][NN*NH]
#define OFF_P    (OFF_AD + 2*NN*NH)       // [2][NR*NK]
#define OFF_PART (OFF_P + 2*NR*NK)        // [2][NR][NCH][128]
#define OFF_S    (OFF_PART + 2*NR*NCH*128)// [2][NN*64] uints (2 bf16 each)
#define OFF_INT  (OFF_S + 2*NN*64)
// int region (relative to OFF_INT) -- first three zeroed together (474 ints)
#define IOFF_RHIST  0                       // 2*NR
#define IOFF_BCUR   (2*NR)                  // 2*NB
#define IOFF_RCUR   (2*NR + 2*NB)           // 2*NR
#define IOFF_START  (IOFF_RCUR + 2*NR)      // 2*NN (absolute into srcs)
#define IOFF_DEG    (IOFF_START + 2*NN)     // 2*NN
#define IOFF_NID    (IOFF_DEG + 2*NN)       // 2*NN
#define IOFF_BINNED (IOFF_NID + 2*NN)       // 2*NB*SLOT
#define IOFF_SRC    (IOFF_BINNED + 2*NB*SLOT) // 2*NB*SLOT + 1 (sentinel)

static __device__ __forceinline__ unsigned int f2bf(float v) {
    unsigned int x = __float_as_uint(v);
    return (x + 0x7FFFu + ((x >> 16) & 1u)) >> 16;   // round-nearest-even
}
static __device__ __forceinline__ float bf2f(unsigned int u) {
    return __uint_as_float(u << 16);
}

// zero the atomic-counter arrays + write srcs end-sentinel
__global__ __launch_bounds__(512) void k_zero(int* __restrict__ p,
                                              int* __restrict__ srcs) {
    int i = threadIdx.x;
    if (i < 2 * NR + 2 * NB + 2 * NR) p[i] = 0;
    if (i == 0) srcs[2 * NB * SLOT] = 0;   // clamped reads of 0-deg dsts land here
}

// fused front: blocks [0,2*GAB) = per-node a_s/a_d + route hist;
//              blocks [2*GAB, ...) = edge coarse-binning
__global__ __launch_bounds__(1024) void k_front(const float* __restrict__ x1,
                                                const float* __restrict__ x2,
                                                const int* __restrict__ rv1,
                                                const int* __restrict__ rv2,
                                                const int* __restrict__ ei1,
                                                const int* __restrict__ ei2,
                                                const float* __restrict__ W,
                                                const float* __restrict__ asrc,
                                                const float* __restrict__ adst,
                                                float* __restrict__ as_,
                                                float* __restrict__ ad_,
                                                int* __restrict__ rhist,
                                                int* __restrict__ bcur,
                                                unsigned int* __restrict__ binned) {
    __shared__ float us[256];
    __shared__ int lh[NR];
    __shared__ int lhb[NB], lbb[NB];
    int tid = threadIdx.x;
    if (blockIdx.x < 2 * GAB) {
        // ---- k_a path: 1024 nodes per block ----
        if (tid < NR) lh[tid] = 0;
        if (tid < 256) {
            int tt = tid & 127;
            int f = tt >> 3, h = tt & 7;
            const float* av = (tid < 128 ? asrc : adst) + h * 64;
            const float* wrow = W + f * 512 + h * 64;
            float su = 0.f;
            for (int c = 0; c < 64; ++c) su += wrow[c] * av[c];
            us[tid] = su;  // [0:128)=u_src(f,h), [128:256)=u_dst(f,h)
        }
        __syncthreads();
        int g = blockIdx.x / GAB;
        int n = (blockIdx.x - g * GAB) * 1024 + tid;
        if (n < NN) {
            const float* x = g ? x2 : x1;
            const int* rv = g ? rv2 : rv1;
            const float4* xp = (const float4*)(x + n * NF);
            float4 v0 = xp[0], v1 = xp[1], v2 = xp[2], v3 = xp[3];
            float xv[16] = {v0.x, v0.y, v0.z, v0.w, v1.x, v1.y, v1.z, v1.w,
                            v2.x, v2.y, v2.z, v2.w, v3.x, v3.y, v3.z, v3.w};
            int o = g * NN * NH + n * NH;
            for (int h = 0; h < NH; ++h) {
                float s1 = 0.f, s2 = 0.f;
                for (int f = 0; f < NF; ++f) {
                    s1 += xv[f] * us[f * 8 + h];
                    s2 += xv[f] * us[128 + f * 8 + h];
                }
                as_[o + h] = s1;
                ad_[o + h] = s2;
            }
            atomicAdd(&lh[rv[n]], 1);
        }
        __syncthreads();
        if (tid < NR && lh[tid]) atomicAdd(&rhist[g * NR + tid], lh[tid]);
    } else {
        // ---- k_bin path ----
        int bid = blockIdx.x - 2 * GAB;
        int g = bid >= BPG;
        int blk = bid - g * BPG;
        if (tid < NB) lhb[tid] = 0;
        __syncthreads();
        int e = blk * 1024 + tid;
        const int* ei = g ? ei2 : ei1;
        unsigned int v = 0;
        int bin = 0, lpos = 0;
        bool valid = (e < NE);
        if (valid) {
            unsigned int s = (unsigned int)ei[e];
            unsigned int dv = (unsigned int)ei[NE + e];
            v = (dv << 16) | s;
            bin = dv >> 8;
            lpos = atomicAdd(&lhb[bin], 1);
        }
        __syncthreads();
        if (tid < NB && lhb[tid]) lbb[tid] = atomicAdd(&bcur[g * NB + tid], lhb[tid]);
        __syncthreads();
        if (valid) {
            int p = lbb[bin] + lpos;
            if (p < SLOT) binned[(g * NB + bin) * SLOT + p] = v;
        }
    }
}

// fused mid: blocks [0,2*NB) = per-bucket fine sort -> srcs/start/deg;
//            blocks [2*NB, ...) = route counting-sort of node ids
__global__ __launch_bounds__(256) void k_mid(const int* __restrict__ bcur,
                                             const unsigned int* __restrict__ binned,
                                             const int* __restrict__ rv1,
                                             const int* __restrict__ rv2,
                                             const int* __restrict__ rhist,
                                             int* __restrict__ rcur,
                                             int* __restrict__ start,
                                             int* __restrict__ deg,
                                             int* __restrict__ srcs,
                                             int* __restrict__ nid) {
    __shared__ unsigned int ed[SLOT];
    __shared__ int hist[256], scn[256];
    __shared__ int lh[NR], lbase[NR], rbase[NR];
    int tid = threadIdx.x;
    if (blockIdx.x < 2 * NB) {
        // ---- fine-sort path ----
        int gb = blockIdx.x;
        int g = gb >= NB;
        int b = gb - g * NB;
        int m = bcur[gb]; if (m > SLOT) m = SLOT;
        int base = gb * SLOT;
        for (int i = tid; i < m; i += 256) ed[i] = binned[base + i];
        hist[tid] = 0;
        __syncthreads();
        for (int i = tid; i < m; i += 256) atomicAdd(&hist[(ed[i] >> 16) & 255], 1);
        __syncthreads();
        int v = hist[tid];
        scn[tid] = v;
        __syncthreads();
        for (int off = 1; off < 256; off <<= 1) {
            int u = (tid >= off) ? scn[tid - off] : 0;
            __syncthreads();
            scn[tid] += u;
            __syncthreads();
        }
        int excl = scn[tid] - v;
        int d = b * 256 + tid;
        if (d < NN) { start[g * NN + d] = base + excl; deg[g * NN + d] = v; }
        hist[tid] = excl;              // reuse as cursor
        __syncthreads();
        for (int i = tid; i < m; i += 256) {
            unsigned int e = ed[i];
            int ld = (e >> 16) & 255;
            int pos = atomicAdd(&hist[ld], 1);
            srcs[base + pos] = (int)(e & 0xffffu);
        }
    } else {
        // ---- node route-sort path ----
        int bid = blockIdx.x - 2 * NB;
        int g = bid / NBLK;
        int n = (bid - g * NBLK) * 256 + tid;
        const int* rv = g ? rv2 : rv1;
        if (tid < NR) lh[tid] = 0;
        __syncthreads();
        int r = 0, lpos = 0;
        bool valid = (n < NN);
        if (valid) { r = rv[n]; lpos = atomicAdd(&lh[r], 1); }
        if (tid == 0) {
            int run = 0;
            for (int rr = 0; rr < NR; ++rr) { rbase[rr] = run; run += rhist[g * NR + rr]; }
        }
        __syncthreads();
        if (tid < NR && lh[tid])
            lbase[tid] = rbase[tid] + atomicAdd(&rcur[g * NR + tid], lh[tid]);
        __syncthreads();
        if (valid) nid[g * NN + lbase[r] + lpos] = n;
    }
}

// gather: one wave per PAIR of adjacent dsts (cross-dst ILP) with XCD-aware
// graph partitioning: blocks with (bid%8)<4 process graph 0, else graph 1,
// so each XCD's random-access tables (x + as_ of ONE graph, ~3.8 MB) fit its
// 4 MB private L2. Bijective remap; lane = (h,q); shfl redistribution.
__global__ __launch_bounds__(256) void k_gather(const int* __restrict__ start,
                                                const int* __restrict__ deg,
                                                const int* __restrict__ srcs,
                                                const float* __restrict__ as_,
                                                const float* __restrict__ ad_,
                                                const float* __restrict__ x1,
                                                const float* __restrict__ x2,
                                                unsigned int* __restrict__ sb) {
    int bid = blockIdx.x;                    // [0, NN/4) = 10000
    int xcd = bid & 7;
    int g = xcd >> 2;                        // graph pinned to XCD group
    int lblk = (xcd & 3) * (NN / 32) + (bid >> 3);   // [0, 5000)
    int pair = lblk * 4 + (threadIdx.x >> 6);        // [0, 20000)
    int d0 = pair * 2, d1 = d0 + 1;
    int idx0 = g * NN + d0, idx1 = idx0 + 1;
    const float* x = g ? x2 : x1;
    const float* asg = as_ + (size_t)g * NN * NH;
    const float* adg = ad_ + (size_t)g * NN * NH;
    int lane = threadIdx.x & 63;
    int h = lane >> 3, q = lane & 7;
    // issue both dsts' setup loads together
    int base0 = __builtin_amdgcn_readfirstlane(start[idx0]);
    int dg0   = __builtin_amdgcn_readfirstlane(deg[idx0]);
    int base1 = __builtin_amdgcn_readfirstlane(start[idx1]);
    int dg1   = __builtin_amdgcn_readfirstlane(deg[idx1]);
    float adv0 = adg[d0 * NH + h];
    float adv1 = adg[d1 * NH + h];
    float as0 = asg[d0 * NH + h];
    float as1 = asg[d1 * NH + h];
    float2 xv0 = *(const float2*)(x + d0 * NF + q * 2);
    float2 xv1 = *(const float2*)(x + d1 * NF + q * 2);
    float e00 = as0 + adv0; e00 = (e00 > 0.f) ? e00 : NEG * e00;
    float e01 = as1 + adv1; e01 = (e01 > 0.f) ? e01 : NEG * e01;
    float w00 = __expf(e00), w01 = __expf(e01);
    float ws0 = w00, ax0 = w00 * xv0.x, ay0 = w00 * xv0.y;
    float ws1 = w01, ax1 = w01 * xv1.x, ay1 = w01 * xv1.y;
    int nb0 = (dg0 + 7) >> 3, nb1 = (dg1 + 7) >> 3;
    int nb = (nb0 > nb1) ? nb0 : nb1;
    for (int b = 0; b < nb; ++b) {
        int lim0 = dg0 - b * 8;               // may be <=0 (masked out)
        int lim1 = dg1 - b * 8;
        int aq0 = (q < lim0) ? base0 + b * 8 + q : base0;
        int aq1 = (q < lim1) ? base1 + b * 8 + q : base1;
        int sq0 = srcs[aq0];                  // both loads in flight
        int sq1 = srcs[aq1];
        float ev0 = asg[sq0 * NH + h] + adv0;
        float ev1 = asg[sq1 * NH + h] + adv1;
        ev0 = (ev0 > 0.f) ? ev0 : NEG * ev0;
        ev1 = (ev1 > 0.f) ? ev1 : NEG * ev1;
        float wq0 = (q < lim0) ? __expf(ev0) : 0.f;
        float wq1 = (q < lim1) ? __expf(ev1) : 0.f;
        int sB0 = __shfl(sq0, lane >> 3);
        int sB1 = __shfl(sq1, lane >> 3);
        float2 xr0 = *(const float2*)(x + sB0 * NF + q * 2);
        float2 xr1 = *(const float2*)(x + sB1 * NF + q * 2);
        #pragma unroll
        for (int j = 0; j < 8; ++j) {
            float wj0 = __shfl(wq0,   (lane & 56) | j);
            float wj1 = __shfl(wq1,   (lane & 56) | j);
            float xx0 = __shfl(xr0.x, (j << 3) | q);
            float xy0 = __shfl(xr0.y, (j << 3) | q);
            float xx1 = __shfl(xr1.x, (j << 3) | q);
            float xy1 = __shfl(xr1.y, (j << 3) | q);
            ws0 += wj0; ax0 += wj0 * xx0; ay0 += wj0 * xy0;
            ws1 += wj1; ax1 += wj1 * xx1; ay1 += wj1 * xy1;
        }
    }
    float inv0 = 1.0f / ws0, inv1 = 1.0f / ws1;
    unsigned int pk0 = (f2bf(ay0 * inv0) << 16) | f2bf(ax0 * inv0);
    unsigned int pk1 = (f2bf(ay1 * inv1) << 16) | f2bf(ax1 * inv1);
    sb[(size_t)idx0 * 64 + lane] = pk0;
    sb[(size_t)idx1 * 64 + lane] = pk1;
}

// route-sorted register accumulation, XCD-pinned per graph like k_gather
__global__ __launch_bounds__(256) void k_rnode(const int* __restrict__ rhist,
                                               const int* __restrict__ nid,
                                               const unsigned int* __restrict__ sb,
                                               float* __restrict__ part) {
    __shared__ float red[4][128];
    __shared__ int sseg[2];
    int bid = blockIdx.x;                    // [0, 2*NR*NCH) = 1280
    int xcd = bid & 7;
    int g = xcd >> 2;
    int rch = (xcd & 3) * (NR * NCH / 4) + (bid >> 3);   // [0, 640)
    int r = rch / NCH, ch = rch - r * NCH;
    if (threadIdx.x == 0) {
        int acc = 0;
        for (int rr = 0; rr < r; ++rr) acc += rhist[g * NR + rr];
        sseg[0] = acc;
        sseg[1] = rhist[g * NR + r];
    }
    __syncthreads();
    int seg0 = sseg[0], dgr = sseg[1];
    int csz = (dgr + NCH - 1) / NCH;
    int a = seg0 + ch * csz;
    int b = seg0 + dgr; { int bb = a + csz; if (bb < b) b = bb; }
    int ln = threadIdx.x >> 6, c = threadIdx.x & 63;
    const int* np = nid + g * NN;
    const unsigned int* sg = sb + (size_t)g * NN * 64;
    float sx = 0.f, sy = 0.f;
    for (int i = a + ln; i < b; i += 4) {
        int n = np[i];
        unsigned int pk = sg[(size_t)n * 64 + c];
        sx += bf2f(pk & 0xffffu);
        sy += bf2f(pk >> 16);
    }
    red[ln][c * 2] = sx;
    red[ln][c * 2 + 1] = sy;
    __syncthreads();
    int tid = threadIdx.x;
    if (tid < 128) {
        float s = red[0][tid] + red[1][tid] + red[2][tid] + red[3][tid];
        part[((g * NR + r) * NCH + ch) * 128 + tid] = s;
    }
}

// fused: chunk-partial reduce -> t row -> agg row (512) -> P[g,i,k]
__global__ __launch_bounds__(256) void k_head(const float* __restrict__ part,
                                              const int* __restrict__ rhist,
                                              const float* __restrict__ W,
                                              const float* __restrict__ bias,
                                              const float* __restrict__ Wh,
                                              float* __restrict__ P) {
    __shared__ float trow[128];
    __shared__ float aggL[512];
    __shared__ float scnt;
    int g = blockIdx.x / NR, i = blockIdx.x - g * NR;
    int tid = threadIdx.x;
    if (tid < 128) {
        const float* pp = part + ((g * NR + i) * NCH) * 128 + tid;
        float s = 0.f;
        for (int ch = 0; ch < NCH; ++ch) s += pp[ch * 128];
        trow[tid] = s;
    }
    if (tid == 0) scnt = (float)rhist[g * NR + i];
    __syncthreads();
    for (int hc = tid; hc < 512; hc += 256) {
        int h = hc >> 6;
        float acc = scnt * bias[hc];
        const float* tp = trow + h * 16;
        for (int f = 0; f < 16; ++f) acc += tp[f] * W[f * 512 + hc];
        aggL[hc] = acc;
    }
    __syncthreads();
    if (tid < 4 * NK) {
        int k = tid >> 2, qq = tid & 3;
        const float* wp = Wh + (size_t)(g * 512 + qq * 128) * 61 + k;
        const float* ap = aggL + qq * 128;
        float acc = 0.f;
        for (int d = 0; d < 128; ++d) acc += ap[d] * wp[d * 61];
        acc += __shfl_down(acc, 1);
        acc += __shfl_down(acc, 2);
        if (qq == 0) P[(g * NR + i) * NK + k] = acc;
    }
}

// factorized global softmax: logits = p1[i,k]+p2[j,k]+b[k]
//   max and denom factorize per-k; out = e1[i,k]*e2[j,k]*f[k]
__global__ __launch_bounds__(1024) void k_final(const float* __restrict__ P,
                                                const float* __restrict__ bh,
                                                float* __restrict__ out) {
    __shared__ float p1[NR * NK], p2[NR * NK];     // overwritten with e1,e2
    __shared__ float ak[NK], ck[NK], s1k[NK], s2k[NK];
    __shared__ float fk[NK];
    int tid = threadIdx.x;
    for (int i = tid; i < NR * NK; i += 1024) { p1[i] = P[i]; p2[i] = P[NR * NK + i]; }
    __syncthreads();
    if (tid < 2 * NK) {
        int k = (tid < NK) ? tid : tid - NK;
        float* pp = (tid < NK) ? p1 : p2;
        float a = -3.0e38f;
        for (int i = 0; i < NR; ++i) a = fmaxf(a, pp[i * NK + k]);
        float s = 0.f;
        for (int i = 0; i < NR; ++i) {
            float e = __expf(pp[i * NK + k] - a);
            pp[i * NK + k] = e;                    // p -> e in place
            s += e;
        }
        if (tid < NK) { ak[k] = a; s1k[k] = s; }
        else          { ck[k] = a; s2k[k] = s; }
    }
    __syncthreads();
    if (tid == 0) {
        float M = -3.0e38f;
        float mk[NK];
        for (int k = 0; k < NK; ++k) {
            mk[k] = ak[k] + ck[k] + bh[k];
            M = fmaxf(M, mk[k]);
        }
        float den = 0.f;
        for (int k = 0; k < NK; ++k) den += s1k[k] * s2k[k] * __expf(mk[k] - M);
        float invden = 1.0f / den;
        for (int k = 0; k < NK; ++k) fk[k] = __expf(mk[k] - M) * invden;
    }
    __syncthreads();
    const int TOT = NR * NR * NK;
    for (int idx = tid; idx < TOT; idx += 1024) {
        int i = idx / (NR * NK);
        int r = idx - i * (NR * NK);
        int j = r / NK;
        int k = r - j * NK;
        out[idx] = p1[i * NK + k] * p2[j * NK + k] * fk[k];
    }
}

extern "C" void kernel_launch(void* const* d_in, const int* in_sizes, int n_in,
                              void* d_out, int out_size, void* d_ws, size_t ws_size,
                              hipStream_t stream) {
    const float* x1   = (const float*)d_in[0];
    const int*   ei1  = (const int*)d_in[1];
    const int*   rv1  = (const int*)d_in[3];
    const float* x2   = (const float*)d_in[5];
    const int*   ei2  = (const int*)d_in[6];
    const int*   rv2  = (const int*)d_in[8];
    const float* Wg   = (const float*)d_in[10];
    const float* asrc = (const float*)d_in[11];
    const float* adst = (const float*)d_in[12];
    const float* bias = (const float*)d_in[13];
    const float* Wh   = (const float*)d_in[14];
    const float* bh   = (const float*)d_in[15];
    float* out = (float*)d_out;
    float* ws  = (float*)d_ws;

    float* as_  = ws + OFF_AS;
    float* ad_  = ws + OFF_AD;
    float* P    = ws + OFF_P;
    float* part = ws + OFF_PART;
    unsigned int* sb = (unsigned int*)(ws + OFF_S);
    int* ibase  = (int*)(ws + OFF_INT);
    int* rhist  = ibase + IOFF_RHIST;
    int* bcur   = ibase + IOFF_BCUR;
    int* rcur   = ibase + IOFF_RCUR;
    int* start  = ibase + IOFF_START;
    int* deg    = ibase + IOFF_DEG;
    int* nid    = ibase + IOFF_NID;
    unsigned int* binned = (unsigned int*)(ibase + IOFF_BINNED);
    int* srcs   = ibase + IOFF_SRC;

    k_zero<<<1, 512, 0, stream>>>(rhist, srcs);
    k_front<<<2 * GAB + 2 * BPG, 1024, 0, stream>>>(x1, x2, rv1, rv2, ei1, ei2,
                                                    Wg, asrc, adst, as_, ad_,
                                                    rhist, bcur, binned);
    k_mid<<<2 * NB + 2 * NBLK, 256, 0, stream>>>(bcur, binned, rv1, rv2, rhist,
                                                 rcur, start, deg, srcs, nid);
    k_gather<<<NN / 4, 256, 0, stream>>>(start, deg, srcs, as_, ad_, x1, x2, sb);
    k_rnode<<<2 * NR * NCH, 256, 0, stream>>>(rhist, nid, sb, part);
    k_head<<<2 * NR, 256, 0, stream>>>(part, rhist, Wg, bias, Wh, P);
    k_final<<<1, 1024, 0, stream>>>(P, bh, out);
}

// Round 14
// 107.483 us; speedup vs baseline: 1.4096x; 1.1129x over previous
//
#include <hip/hip_runtime.h>
#include <hip/hip_fp16.h>

#define NN 40000      // nodes
#define NE 400000     // edges (before self loops)
#define NF 16         // in features
#define NH 8          // heads
#define NR 40         // routes
#define NK 39         // min(R1,R2)-1 logits kept
#define NEG 0.2f      // leaky relu slope
#define NBLK 157      // (NN+255)/256
#define NCH 16        // chunks per route
#define NB 157        // coarse buckets per graph (dst>>8)
#define SLOT 3328     // entries per bucket slot (mean 2560, +15 sigma)
#define BPG 391       // (NE+1023)/1024 blocks per graph
#define GAB 40        // (NN+1023)/1024 blocks per graph for k_a path

// float region offsets
#define OFF_AS   0                        // [2][NN*NH]
#define OFF_AD   (OFF_AS + 2*NN*NH)       // [2][NN*NH]
#define OFF_P    (OFF_AD + 2*NN*NH)       // [2][NR*NK]
#define OFF_PART (OFF_P + 2*NR*NK)        // [2][NR][NCH][128]
#define OFF_S    (OFF_PART + 2*NR*NCH*128)// [2][NN*64] uints (2 bf16 each)
#define OFF_XH   (OFF_S + 2*NN*64)        // [2][NN*8] uints (2 fp16 each)
#define OFF_INT  (OFF_XH + 2*NN*8)
// int region (relative to OFF_INT) -- first three zeroed together (474 ints)
#define IOFF_RHIST  0                       // 2*NR
#define IOFF_BCUR   (2*NR)                  // 2*NB
#define IOFF_RCUR   (2*NR + 2*NB)           // 2*NR
#define IOFF_START  (IOFF_RCUR + 2*NR)      // 2*NN (absolute into srcs)
#define IOFF_DEG    (IOFF_START + 2*NN)     // 2*NN
#define IOFF_NID    (IOFF_DEG + 2*NN)       // 2*NN
#define IOFF_BINNED (IOFF_NID + 2*NN)       // 2*NB*SLOT
#define IOFF_SRC    (IOFF_BINNED + 2*NB*SLOT) // 2*NB*SLOT + 1 (sentinel)

static __device__ __forceinline__ unsigned int f2bf(float v) {
    unsigned int x = __float_as_uint(v);
    return (x + 0x7FFFu + ((x >> 16) & 1u)) >> 16;   // round-nearest-even
}
static __device__ __forceinline__ float bf2f(unsigned int u) {
    return __uint_as_float(u << 16);
}
static __device__ __forceinline__ unsigned int packh2(float a, float b) {
    __half2 hv = __floats2half2_rn(a, b);            // ROCm: (float, float)
    return *(unsigned int*)&hv;
}
static __device__ __forceinline__ float2 unpackh2(unsigned int u) {
    __half2 hv = *(__half2*)&u;
    return __half22float2(hv);
}

// zero the atomic-counter arrays + write srcs end-sentinel
__global__ __launch_bounds__(512) void k_zero(int* __restrict__ p,
                                              int* __restrict__ srcs) {
    int i = threadIdx.x;
    if (i < 2 * NR + 2 * NB + 2 * NR) p[i] = 0;
    if (i == 0) srcs[2 * NB * SLOT] = 0;
}

// fused front: blocks [0,2*GAB) = per-node a_s/a_d + route hist + fp16 x-pack;
//              blocks [2*GAB, ...) = edge coarse-binning
__global__ __launch_bounds__(1024) void k_front(const float* __restrict__ x1,
                                                const float* __restrict__ x2,
                                                const int* __restrict__ rv1,
                                                const int* __restrict__ rv2,
                                                const int* __restrict__ ei1,
                                                const int* __restrict__ ei2,
                                                const float* __restrict__ W,
                                                const float* __restrict__ asrc,
                                                const float* __restrict__ adst,
                                                float* __restrict__ as_,
                                                float* __restrict__ ad_,
                                                unsigned int* __restrict__ xh,
                                                int* __restrict__ rhist,
                                                int* __restrict__ bcur,
                                                unsigned int* __restrict__ binned) {
    __shared__ float us[256];
    __shared__ int lh[NR];
    __shared__ int lhb[NB], lbb[NB];
    int tid = threadIdx.x;
    if (blockIdx.x < 2 * GAB) {
        // ---- k_a path: 1024 nodes per block ----
        if (tid < NR) lh[tid] = 0;
        if (tid < 256) {
            int tt = tid & 127;
            int f = tt >> 3, h = tt & 7;
            const float* av = (tid < 128 ? asrc : adst) + h * 64;
            const float* wrow = W + f * 512 + h * 64;
            float su = 0.f;
            for (int c = 0; c < 64; ++c) su += wrow[c] * av[c];
            us[tid] = su;  // [0:128)=u_src(f,h), [128:256)=u_dst(f,h)
        }
        __syncthreads();
        int g = blockIdx.x / GAB;
        int n = (blockIdx.x - g * GAB) * 1024 + tid;
        if (n < NN) {
            const float* x = g ? x2 : x1;
            const int* rv = g ? rv2 : rv1;
            const float4* xp = (const float4*)(x + n * NF);
            float4 v0 = xp[0], v1 = xp[1], v2 = xp[2], v3 = xp[3];
            float xv[16] = {v0.x, v0.y, v0.z, v0.w, v1.x, v1.y, v1.z, v1.w,
                            v2.x, v2.y, v2.z, v2.w, v3.x, v3.y, v3.z, v3.w};
            int o = g * NN * NH + n * NH;
            for (int h = 0; h < NH; ++h) {
                float s1 = 0.f, s2 = 0.f;
                for (int f = 0; f < NF; ++f) {
                    s1 += xv[f] * us[f * 8 + h];
                    s2 += xv[f] * us[128 + f * 8 + h];
                }
                as_[o + h] = s1;
                ad_[o + h] = s2;
            }
            unsigned int* xo = xh + ((size_t)g * NN + n) * 8;
            #pragma unroll
            for (int p = 0; p < 8; ++p) xo[p] = packh2(xv[2 * p], xv[2 * p + 1]);
            atomicAdd(&lh[rv[n]], 1);
        }
        __syncthreads();
        if (tid < NR && lh[tid]) atomicAdd(&rhist[g * NR + tid], lh[tid]);
    } else {
        // ---- k_bin path ----
        int bid = blockIdx.x - 2 * GAB;
        int g = bid >= BPG;
        int blk = bid - g * BPG;
        if (tid < NB) lhb[tid] = 0;
        __syncthreads();
        int e = blk * 1024 + tid;
        const int* ei = g ? ei2 : ei1;
        unsigned int v = 0;
        int bin = 0, lpos = 0;
        bool valid = (e < NE);
        if (valid) {
            unsigned int s = (unsigned int)ei[e];
            unsigned int dv = (unsigned int)ei[NE + e];
            v = (dv << 16) | s;
            bin = dv >> 8;
            lpos = atomicAdd(&lhb[bin], 1);
        }
        __syncthreads();
        if (tid < NB && lhb[tid]) lbb[tid] = atomicAdd(&bcur[g * NB + tid], lhb[tid]);
        __syncthreads();
        if (valid) {
            int p = lbb[bin] + lpos;
            if (p < SLOT) binned[(g * NB + bin) * SLOT + p] = v;
        }
    }
}

// fused mid: blocks [0,2*NB) = per-bucket fine sort -> srcs/start/deg;
//            blocks [2*NB, ...) = route counting-sort of node ids
__global__ __launch_bounds__(256) void k_mid(const int* __restrict__ bcur,
                                             const unsigned int* __restrict__ binned,
                                             const int* __restrict__ rv1,
                                             const int* __restrict__ rv2,
                                             const int* __restrict__ rhist,
                                             int* __restrict__ rcur,
                                             int* __restrict__ start,
                                             int* __restrict__ deg,
                                             int* __restrict__ srcs,
                                             int* __restrict__ nid) {
    __shared__ unsigned int ed[SLOT];
    __shared__ int hist[256], scn[256];
    __shared__ int lh[NR], lbase[NR], rbase[NR];
    int tid = threadIdx.x;
    if (blockIdx.x < 2 * NB) {
        // ---- fine-sort path ----
        int gb = blockIdx.x;
        int g = gb >= NB;
        int b = gb - g * NB;
        int m = bcur[gb]; if (m > SLOT) m = SLOT;
        int base = gb * SLOT;
        for (int i = tid; i < m; i += 256) ed[i] = binned[base + i];
        hist[tid] = 0;
        __syncthreads();
        for (int i = tid; i < m; i += 256) atomicAdd(&hist[(ed[i] >> 16) & 255], 1);
        __syncthreads();
        int v = hist[tid];
        scn[tid] = v;
        __syncthreads();
        for (int off = 1; off < 256; off <<= 1) {
            int u = (tid >= off) ? scn[tid - off] : 0;
            __syncthreads();
            scn[tid] += u;
            __syncthreads();
        }
        int excl = scn[tid] - v;
        int d = b * 256 + tid;
        if (d < NN) { start[g * NN + d] = base + excl; deg[g * NN + d] = v; }
        hist[tid] = excl;              // reuse as cursor
        __syncthreads();
        for (int i = tid; i < m; i += 256) {
            unsigned int e = ed[i];
            int ld = (e >> 16) & 255;
            int pos = atomicAdd(&hist[ld], 1);
            srcs[base + pos] = (int)(e & 0xffffu);
        }
    } else {
        // ---- node route-sort path ----
        int bid = blockIdx.x - 2 * NB;
        int g = bid / NBLK;
        int n = (bid - g * NBLK) * 256 + tid;
        const int* rv = g ? rv2 : rv1;
        if (tid < NR) lh[tid] = 0;
        __syncthreads();
        int r = 0, lpos = 0;
        bool valid = (n < NN);
        if (valid) { r = rv[n]; lpos = atomicAdd(&lh[r], 1); }
        if (tid == 0) {
            int run = 0;
            for (int rr = 0; rr < NR; ++rr) { rbase[rr] = run; run += rhist[g * NR + rr]; }
        }
        __syncthreads();
        if (tid < NR && lh[tid])
            lbase[tid] = rbase[tid] + atomicAdd(&rcur[g * NR + tid], lh[tid]);
        __syncthreads();
        if (valid) nid[g * NN + lbase[r] + lpos] = n;
    }
}

// gather: ONE dst per 64-lane wave (unpaired, R9 structure) + XCD graph
// pinning ((bid%8)<4 -> graph0). lane = (h,q). Per 8-edge batch:
// 1 srcs + 1 as_ + 1 exp per lane; x rows as fp16-packed u32 -> j-loop is
// 2 shfls (w + packed x) instead of 3. 17 DS ops/batch (was 25).
__global__ __launch_bounds__(256) void k_gather(const int* __restrict__ start,
                                                const int* __restrict__ deg,
                                                const int* __restrict__ srcs,
                                                const float* __restrict__ as_,
                                                const float* __restrict__ ad_,
                                                const unsigned int* __restrict__ xh,
                                                unsigned int* __restrict__ sb) {
    int bid = blockIdx.x;                    // [0, 20000)
    int xcd = bid & 7;
    int g = xcd >> 2;                        // graph pinned to XCD group
    int lblk = (xcd & 3) * 2500 + (bid >> 3);        // [0, 10000)
    int d = lblk * 4 + (threadIdx.x >> 6);           // [0, 40000)
    int idx = g * NN + d;
    const float* asg = as_ + (size_t)g * NN * NH;
    const unsigned int* xg = xh + (size_t)g * NN * 8;
    int lane = threadIdx.x & 63;
    int h = lane >> 3, q = lane & 7;
    float adv = ad_[(size_t)g * NN * NH + d * NH + h];
    // self loop
    float e0 = asg[d * NH + h] + adv;
    e0 = (e0 > 0.f) ? e0 : NEG * e0;
    float w0 = __expf(e0);
    float2 xv = unpackh2(xg[d * 8 + q]);
    float wsum = w0;
    float ax = w0 * xv.x, ay = w0 * xv.y;
    int base = __builtin_amdgcn_readfirstlane(start[idx]);
    int dg   = __builtin_amdgcn_readfirstlane(deg[idx]);
    int nb = (dg + 7) >> 3;
    for (int b = 0; b < nb; ++b) {
        int off = base + b * 8;
        int lim = dg - b * 8;                 // >0, wave-uniform
        int aq = (q < lim) ? off + q : base;  // clamp (base valid: dg>0 here)
        int sq = srcs[aq];
        float ev = asg[sq * NH + h] + adv;
        ev = (ev > 0.f) ? ev : NEG * ev;
        float wq = (q < lim) ? __expf(ev) : 0.f;
        int sB = __shfl(sq, lane >> 3);       // s_j in lane (0, q=j)
        unsigned int xu = xg[sB * 8 + q];     // ONE u32 per lane (fp16 pair)
        #pragma unroll
        for (int j = 0; j < 8; ++j) {
            float wj = __shfl(wq, (lane & 56) | j);
            unsigned int xj = (unsigned int)__shfl((int)xu, (j << 3) | q);
            float2 xf = unpackh2(xj);
            wsum += wj;
            ax += wj * xf.x;
            ay += wj * xf.y;
        }
    }
    float inv = 1.0f / wsum;
    unsigned int pk = (f2bf(ay * inv) << 16) | f2bf(ax * inv);
    sb[(size_t)idx * 64 + lane] = pk;
}

// route-sorted register accumulation, XCD-pinned per graph
__global__ __launch_bounds__(256) void k_rnode(const int* __restrict__ rhist,
                                               const int* __restrict__ nid,
                                               const unsigned int* __restrict__ sb,
                                               float* __restrict__ part) {
    __shared__ float red[4][128];
    __shared__ int sseg[2];
    int bid = blockIdx.x;                    // [0, 2*NR*NCH) = 1280
    int xcd = bid & 7;
    int g = xcd >> 2;
    int rch = (xcd & 3) * (NR * NCH / 4) + (bid >> 3);   // [0, 640)
    int r = rch / NCH, ch = rch - r * NCH;
    if (threadIdx.x == 0) {
        int acc = 0;
        for (int rr = 0; rr < r; ++rr) acc += rhist[g * NR + rr];
        sseg[0] = acc;
        sseg[1] = rhist[g * NR + r];
    }
    __syncthreads();
    int seg0 = sseg[0], dgr = sseg[1];
    int csz = (dgr + NCH - 1) / NCH;
    int a = seg0 + ch * csz;
    int b = seg0 + dgr; { int bb = a + csz; if (bb < b) b = bb; }
    int ln = threadIdx.x >> 6, c = threadIdx.x & 63;
    const int* np = nid + g * NN;
    const unsigned int* sg = sb + (size_t)g * NN * 64;
    float sx = 0.f, sy = 0.f;
    for (int i = a + ln; i < b; i += 4) {
        int n = np[i];
        unsigned int pk = sg[(size_t)n * 64 + c];
        sx += bf2f(pk & 0xffffu);
        sy += bf2f(pk >> 16);
    }
    red[ln][c * 2] = sx;
    red[ln][c * 2 + 1] = sy;
    __syncthreads();
    int tid = threadIdx.x;
    if (tid < 128) {
        float s = red[0][tid] + red[1][tid] + red[2][tid] + red[3][tid];
        part[((g * NR + r) * NCH + ch) * 128 + tid] = s;
    }
}

// fused: chunk-partial reduce -> t row -> agg row (512) -> P[g,i,k]
__global__ __launch_bounds__(256) void k_head(const float* __restrict__ part,
                                              const int* __restrict__ rhist,
                                              const float* __restrict__ W,
                                              const float* __restrict__ bias,
                                              const float* __restrict__ Wh,
                                              float* __restrict__ P) {
    __shared__ float trow[128];
    __shared__ float aggL[512];
    __shared__ float scnt;
    int g = blockIdx.x / NR, i = blockIdx.x - g * NR;
    int tid = threadIdx.x;
    if (tid < 128) {
        const float* pp = part + ((g * NR + i) * NCH) * 128 + tid;
        float s = 0.f;
        for (int ch = 0; ch < NCH; ++ch) s += pp[ch * 128];
        trow[tid] = s;
    }
    if (tid == 0) scnt = (float)rhist[g * NR + i];
    __syncthreads();
    for (int hc = tid; hc < 512; hc += 256) {
        int h = hc >> 6;
        float acc = scnt * bias[hc];
        const float* tp = trow + h * 16;
        for (int f = 0; f < 16; ++f) acc += tp[f] * W[f * 512 + hc];
        aggL[hc] = acc;
    }
    __syncthreads();
    if (tid < 4 * NK) {
        int k = tid >> 2, qq = tid & 3;
        const float* wp = Wh + (size_t)(g * 512 + qq * 128) * 61 + k;
        const float* ap = aggL + qq * 128;
        float acc = 0.f;
        for (int d = 0; d < 128; ++d) acc += ap[d] * wp[d * 61];
        acc += __shfl_down(acc, 1);
        acc += __shfl_down(acc, 2);
        if (qq == 0) P[(g * NR + i) * NK + k] = acc;
    }
}

// factorized global softmax: logits = p1[i,k]+p2[j,k]+b[k]
__global__ __launch_bounds__(1024) void k_final(const float* __restrict__ P,
                                                const float* __restrict__ bh,
                                                float* __restrict__ out) {
    __shared__ float p1[NR * NK], p2[NR * NK];     // overwritten with e1,e2
    __shared__ float ak[NK], ck[NK], s1k[NK], s2k[NK];
    __shared__ float fk[NK];
    int tid = threadIdx.x;
    for (int i = tid; i < NR * NK; i += 1024) { p1[i] = P[i]; p2[i] = P[NR * NK + i]; }
    __syncthreads();
    if (tid < 2 * NK) {
        int k = (tid < NK) ? tid : tid - NK;
        float* pp = (tid < NK) ? p1 : p2;
        float a = -3.0e38f;
        for (int i = 0; i < NR; ++i) a = fmaxf(a, pp[i * NK + k]);
        float s = 0.f;
        for (int i = 0; i < NR; ++i) {
            float e = __expf(pp[i * NK + k] - a);
            pp[i * NK + k] = e;
            s += e;
        }
        if (tid < NK) { ak[k] = a; s1k[k] = s; }
        else          { ck[k] = a; s2k[k] = s; }
    }
    __syncthreads();
    if (tid == 0) {
        float M = -3.0e38f;
        float mk[NK];
        for (int k = 0; k < NK; ++k) {
            mk[k] = ak[k] + ck[k] + bh[k];
            M = fmaxf(M, mk[k]);
        }
        float den = 0.f;
        for (int k = 0; k < NK; ++k) den += s1k[k] * s2k[k] * __expf(mk[k] - M);
        float invden = 1.0f / den;
        for (int k = 0; k < NK; ++k) fk[k] = __expf(mk[k] - M) * invden;
    }
    __syncthreads();
    const int TOT = NR * NR * NK;
    for (int idx = tid; idx < TOT; idx += 1024) {
        int i = idx / (NR * NK);
        int r = idx - i * (NR * NK);
        int j = r / NK;
        int k = r - j * NK;
        out[idx] = p1[i * NK + k] * p2[j * NK + k] * fk[k];
    }
}

extern "C" void kernel_launch(void* const* d_in, const int* in_sizes, int n_in,
                              void* d_out, int out_size, void* d_ws, size_t ws_size,
                              hipStream_t stream) {
    const float* x1   = (const float*)d_in[0];
    const int*   ei1  = (const int*)d_in[1];
    const int*   rv1  = (const int*)d_in[3];
    const float* x2   = (const float*)d_in[5];
    const int*   ei2  = (const int*)d_in[6];
    const int*   rv2  = (const int*)d_in[8];
    const float* Wg   = (const float*)d_in[10];
    const float* asrc = (const float*)d_in[11];
    const float* adst = (const float*)d_in[12];
    const float* bias = (const float*)d_in[13];
    const float* Wh   = (const float*)d_in[14];
    const float* bh   = (const float*)d_in[15];
    float* out = (float*)d_out;
    float* ws  = (float*)d_ws;

    float* as_  = ws + OFF_AS;
    float* ad_  = ws + OFF_AD;
    float* P    = ws + OFF_P;
    float* part = ws + OFF_PART;
    unsigned int* sb = (unsigned int*)(ws + OFF_S);
    unsigned int* xh = (unsigned int*)(ws + OFF_XH);
    int* ibase  = (int*)(ws + OFF_INT);
    int* rhist  = ibase + IOFF_RHIST;
    int* bcur   = ibase + IOFF_BCUR;
    int* rcur   = ibase + IOFF_RCUR;
    int* start  = ibase + IOFF_START;
    int* deg    = ibase + IOFF_DEG;
    int* nid    = ibase + IOFF_NID;
    unsigned int* binned = (unsigned int*)(ibase + IOFF_BINNED);
    int* srcs   = ibase + IOFF_SRC;

    k_zero<<<1, 512, 0, stream>>>(rhist, srcs);
    k_front<<<2 * GAB + 2 * BPG, 1024, 0, stream>>>(x1, x2, rv1, rv2, ei1, ei2,
                                                    Wg, asrc, adst, as_, ad_, xh,
                                                    rhist, bcur, binned);
    k_mid<<<2 * NB + 2 * NBLK, 256, 0, stream>>>(bcur, binned, rv1, rv2, rhist,
                                                 rcur, start, deg, srcs, nid);
    k_gather<<<2 * NN / 4, 256, 0, stream>>>(start, deg, srcs, as_, ad_, xh, sb);
    k_rnode<<<2 * NR * NCH, 256, 0, stream>>>(rhist, nid, sb, part);
    k_head<<<2 * NR, 256, 0, stream>>>(part, rhist, Wg, bias, Wh, P);
    k_final<<<1, 1024, 0, stream>>>(P, bh, out);
}

// Round 15
// 97.667 us; speedup vs baseline: 1.5513x; 1.1005x over previous
//
#include <hip/hip_runtime.h>
#include <hip/hip_fp16.h>

#define NN 40000      // nodes
#define NE 400000     // edges (before self loops)
#define NF 16         // in features
#define NH 8          // heads
#define NR 40         // routes
#define NK 39         // min(R1,R2)-1 logits kept
#define NEG 0.2f      // leaky relu slope
#define NBLK 157      // (NN+255)/256
#define NCH 16        // chunks per route
#define NB 157        // coarse buckets per graph (dst>>8)
#define SLOT 3328     // entries per bucket slot (mean 2560, +15 sigma)
#define BPG2 196      // (NE/2+1023)/1024 blocks per graph (2 edges/thread)
#define GAB 40        // (NN+1023)/1024 blocks per graph for k_a path
#define WS 0.0625f    // w prescale for fp16 packing (cancels in out=ax/wsum)

// float region offsets
#define OFF_AS   0                        // [2][NN*NH]
#define OFF_AD   (OFF_AS + 2*NN*NH)       // [2][NN*NH]
#define OFF_P    (OFF_AD + 2*NN*NH)       // [2][NR*NK]
#define OFF_PART (OFF_P + 2*NR*NK)        // [2][NR][NCH][128]
#define OFF_S    (OFF_PART + 2*NR*NCH*128)// [2][NN*64] uints (2 bf16 each)
#define OFF_XH   (OFF_S + 2*NN*64)        // [2][NN*8] uints (2 fp16 each)
#define OFF_INT  (OFF_XH + 2*NN*8)
// int region (relative to OFF_INT) -- first three zeroed together (474 ints)
#define IOFF_RHIST  0                       // 2*NR
#define IOFF_BCUR   (2*NR)                  // 2*NB
#define IOFF_RCUR   (2*NR + 2*NB)           // 2*NR
#define IOFF_START  (IOFF_RCUR + 2*NR)      // 2*NN (absolute into srcs)
#define IOFF_DEG    (IOFF_START + 2*NN)     // 2*NN
#define IOFF_NID    (IOFF_DEG + 2*NN)       // 2*NN
#define IOFF_BINNED (IOFF_NID + 2*NN)       // 2*NB*SLOT
#define IOFF_SRC    (IOFF_BINNED + 2*NB*SLOT) // 2*NB*SLOT + 1 (sentinel)

static __device__ __forceinline__ unsigned int f2bf(float v) {
    unsigned int x = __float_as_uint(v);
    return (x + 0x7FFFu + ((x >> 16) & 1u)) >> 16;   // round-nearest-even
}
static __device__ __forceinline__ float bf2f(unsigned int u) {
    return __uint_as_float(u << 16);
}
static __device__ __forceinline__ unsigned int packh2(float a, float b) {
    __half2 hv = __floats2half2_rn(a, b);            // ROCm: (float, float)
    return *(unsigned int*)&hv;
}
static __device__ __forceinline__ float2 unpackh2(unsigned int u) {
    __half2 hv = *(__half2*)&u;
    return __half22float2(hv);
}

// zero the atomic-counter arrays + write srcs end-sentinel
__global__ __launch_bounds__(512) void k_zero(int* __restrict__ p,
                                              int* __restrict__ srcs) {
    int i = threadIdx.x;
    if (i < 2 * NR + 2 * NB + 2 * NR) p[i] = 0;
    if (i == 0) srcs[2 * NB * SLOT] = 0;
}

// fused front: blocks [0,2*GAB) = per-node a_s/a_d + route hist + fp16 x-pack;
//              blocks [2*GAB, ...) = edge coarse-binning (2 edges/thread)
__global__ __launch_bounds__(1024) void k_front(const float* __restrict__ x1,
                                                const float* __restrict__ x2,
                                                const int* __restrict__ rv1,
                                                const int* __restrict__ rv2,
                                                const int* __restrict__ ei1,
                                                const int* __restrict__ ei2,
                                                const float* __restrict__ W,
                                                const float* __restrict__ asrc,
                                                const float* __restrict__ adst,
                                                float* __restrict__ as_,
                                                float* __restrict__ ad_,
                                                unsigned int* __restrict__ xh,
                                                int* __restrict__ rhist,
                                                int* __restrict__ bcur,
                                                unsigned int* __restrict__ binned) {
    __shared__ float us[256];
    __shared__ int lh[NR];
    __shared__ int lhb[NB], lbb[NB];
    int tid = threadIdx.x;
    if (blockIdx.x < 2 * GAB) {
        // ---- k_a path: 1024 nodes per block ----
        if (tid < NR) lh[tid] = 0;
        if (tid < 256) {
            int tt = tid & 127;
            int f = tt >> 3, h = tt & 7;
            const float* av = (tid < 128 ? asrc : adst) + h * 64;
            const float* wrow = W + f * 512 + h * 64;
            float su = 0.f;
            for (int c = 0; c < 64; ++c) su += wrow[c] * av[c];
            us[tid] = su;  // [0:128)=u_src(f,h), [128:256)=u_dst(f,h)
        }
        __syncthreads();
        int g = blockIdx.x / GAB;
        int n = (blockIdx.x - g * GAB) * 1024 + tid;
        if (n < NN) {
            const float* x = g ? x2 : x1;
            const int* rv = g ? rv2 : rv1;
            const float4* xp = (const float4*)(x + n * NF);
            float4 v0 = xp[0], v1 = xp[1], v2 = xp[2], v3 = xp[3];
            float xv[16] = {v0.x, v0.y, v0.z, v0.w, v1.x, v1.y, v1.z, v1.w,
                            v2.x, v2.y, v2.z, v2.w, v3.x, v3.y, v3.z, v3.w};
            int o = g * NN * NH + n * NH;
            for (int h = 0; h < NH; ++h) {
                float s1 = 0.f, s2 = 0.f;
                for (int f = 0; f < NF; ++f) {
                    s1 += xv[f] * us[f * 8 + h];
                    s2 += xv[f] * us[128 + f * 8 + h];
                }
                as_[o + h] = s1;
                ad_[o + h] = s2;
            }
            unsigned int* xo = xh + ((size_t)g * NN + n) * 8;
            #pragma unroll
            for (int p = 0; p < 8; ++p) xo[p] = packh2(xv[2 * p], xv[2 * p + 1]);
            atomicAdd(&lh[rv[n]], 1);
        }
        __syncthreads();
        if (tid < NR && lh[tid]) atomicAdd(&rhist[g * NR + tid], lh[tid]);
    } else {
        // ---- k_bin path: 2 edges per thread via int2 ----
        int bid = blockIdx.x - 2 * GAB;
        int g = bid >= BPG2;
        int blk = bid - g * BPG2;
        if (tid < NB) lhb[tid] = 0;
        __syncthreads();
        int e2 = blk * 1024 + tid;               // edge-pair id
        const int* ei = g ? ei2 : ei1;
        unsigned int v0 = 0, v1 = 0;
        int bin0 = 0, bin1 = 0, lp0 = 0, lp1 = 0;
        bool valid = (e2 < NE / 2);
        if (valid) {
            int2 sv = *(const int2*)&ei[2 * e2];
            int2 dv = *(const int2*)&ei[NE + 2 * e2];
            v0 = ((unsigned int)dv.x << 16) | (unsigned int)sv.x;
            v1 = ((unsigned int)dv.y << 16) | (unsigned int)sv.y;
            bin0 = (unsigned int)dv.x >> 8;
            bin1 = (unsigned int)dv.y >> 8;
            lp0 = atomicAdd(&lhb[bin0], 1);
            lp1 = atomicAdd(&lhb[bin1], 1);
        }
        __syncthreads();
        if (tid < NB && lhb[tid]) lbb[tid] = atomicAdd(&bcur[g * NB + tid], lhb[tid]);
        __syncthreads();
        if (valid) {
            int p0 = lbb[bin0] + lp0;
            int p1 = lbb[bin1] + lp1;
            if (p0 < SLOT) binned[(g * NB + bin0) * SLOT + p0] = v0;
            if (p1 < SLOT) binned[(g * NB + bin1) * SLOT + p1] = v1;
        }
    }
}

// fused mid: blocks [0,2*NB) = per-bucket fine sort -> srcs/start/deg;
//            blocks [2*NB, ...) = route counting-sort of node ids
__global__ __launch_bounds__(256) void k_mid(const int* __restrict__ bcur,
                                             const unsigned int* __restrict__ binned,
                                             const int* __restrict__ rv1,
                                             const int* __restrict__ rv2,
                                             const int* __restrict__ rhist,
                                             int* __restrict__ rcur,
                                             int* __restrict__ start,
                                             int* __restrict__ deg,
                                             int* __restrict__ srcs,
                                             int* __restrict__ nid) {
    __shared__ unsigned int ed[SLOT];
    __shared__ int hist[256], scn[256];
    __shared__ int lh[NR], lbase[NR], rbase[NR];
    int tid = threadIdx.x;
    if (blockIdx.x < 2 * NB) {
        // ---- fine-sort path ----
        int gb = blockIdx.x;
        int g = gb >= NB;
        int b = gb - g * NB;
        int m = bcur[gb]; if (m > SLOT) m = SLOT;
        int base = gb * SLOT;
        for (int i = tid; i < m; i += 256) ed[i] = binned[base + i];
        hist[tid] = 0;
        __syncthreads();
        for (int i = tid; i < m; i += 256) atomicAdd(&hist[(ed[i] >> 16) & 255], 1);
        __syncthreads();
        int v = hist[tid];
        scn[tid] = v;
        __syncthreads();
        for (int off = 1; off < 256; off <<= 1) {
            int u = (tid >= off) ? scn[tid - off] : 0;
            __syncthreads();
            scn[tid] += u;
            __syncthreads();
        }
        int excl = scn[tid] - v;
        int d = b * 256 + tid;
        if (d < NN) { start[g * NN + d] = base + excl; deg[g * NN + d] = v; }
        hist[tid] = excl;              // reuse as cursor
        __syncthreads();
        for (int i = tid; i < m; i += 256) {
            unsigned int e = ed[i];
            int ld = (e >> 16) & 255;
            int pos = atomicAdd(&hist[ld], 1);
            srcs[base + pos] = (int)(e & 0xffffu);
        }
    } else {
        // ---- node route-sort path ----
        int bid = blockIdx.x - 2 * NB;
        int g = bid / NBLK;
        int n = (bid - g * NBLK) * 256 + tid;
        const int* rv = g ? rv2 : rv1;
        if (tid < NR) lh[tid] = 0;
        __syncthreads();
        int r = 0, lpos = 0;
        bool valid = (n < NN);
        if (valid) { r = rv[n]; lpos = atomicAdd(&lh[r], 1); }
        if (tid == 0) {
            int run = 0;
            for (int rr = 0; rr < NR; ++rr) { rbase[rr] = run; run += rhist[g * NR + rr]; }
        }
        __syncthreads();
        if (tid < NR && lh[tid])
            lbase[tid] = rbase[tid] + atomicAdd(&rcur[g * NR + tid], lh[tid]);
        __syncthreads();
        if (valid) nid[g * NN + lbase[r] + lpos] = n;
    }
}

// gather: ONE dst per 64-lane wave + XCD graph pinning. lane = (h,q).
// Per 8-edge batch: srcs x2 (same cacheline), as_ x1, exp x1; w packed in
// fp16 pairs (prescaled by WS, cancels in out=ax/wsum): 1 shfl_xor + 4 pair
// shfls + 8 x shfls = 13 DS ops (was 17).
__global__ __launch_bounds__(256) void k_gather(const int* __restrict__ start,
                                                const int* __restrict__ deg,
                                                const int* __restrict__ srcs,
                                                const float* __restrict__ as_,
                                                const float* __restrict__ ad_,
                                                const unsigned int* __restrict__ xh,
                                                unsigned int* __restrict__ sb) {
    int bid = blockIdx.x;                    // [0, 20000)
    int xcd = bid & 7;
    int g = xcd >> 2;                        // graph pinned to XCD group
    int lblk = (xcd & 3) * 2500 + (bid >> 3);        // [0, 10000)
    int d = lblk * 4 + (threadIdx.x >> 6);           // [0, 40000)
    int idx = g * NN + d;
    const float* asg = as_ + (size_t)g * NN * NH;
    const unsigned int* xg = xh + (size_t)g * NN * 8;
    int lane = threadIdx.x & 63;
    int h = lane >> 3, q = lane & 7;
    int a8 = lane >> 3;                      // row slot this lane loads x for
    float adv = ad_[(size_t)g * NN * NH + d * NH + h];
    // self loop (prescaled by WS; cancels in the final divide)
    float e0 = asg[d * NH + h] + adv;
    e0 = (e0 > 0.f) ? e0 : NEG * e0;
    float w0 = __expf(e0) * WS;
    float2 xv = unpackh2(xg[d * 8 + q]);
    float wsum = w0;
    float ax = w0 * xv.x, ay = w0 * xv.y;
    int base = __builtin_amdgcn_readfirstlane(start[idx]);
    int dg   = __builtin_amdgcn_readfirstlane(deg[idx]);
    int nb = (dg + 7) >> 3;
    for (int b = 0; b < nb; ++b) {
        int off = base + b * 8;
        int lim = dg - b * 8;                 // >0, wave-uniform
        int aq = (q < lim) ? off + q : base;  // clamp (base valid: dg>0 here)
        int aA = (a8 < lim) ? off + a8 : base;
        int sq = srcs[aq];                    // weight-slot src
        int sA = srcs[aA];                    // x-row src (same cacheline)
        float ev = asg[sq * NH + h] + adv;
        ev = (ev > 0.f) ? ev : NEG * ev;
        float wq = (q < lim) ? __expf(ev) * WS : 0.f;
        // pack w pair (w[2p], w[2p+1]) as fp16x2 in both lanes of the pair
        float wpart = __shfl_xor(wq, 1);
        unsigned int wpair = (q & 1) ? packh2(wpart, wq) : packh2(wq, wpart);
        unsigned int xu = xg[sA * 8 + q];     // fp16 pair of row s_a
        #pragma unroll
        for (int p = 0; p < 4; ++p) {
            unsigned int wp = (unsigned int)__shfl((int)wpair, (lane & 56) | (p << 1));
            float2 wf = unpackh2(wp);
            unsigned int xj0 = (unsigned int)__shfl((int)xu, ((p << 1) << 3) | q);
            unsigned int xj1 = (unsigned int)__shfl((int)xu, (((p << 1) | 1) << 3) | q);
            float2 x0 = unpackh2(xj0);
            float2 x1 = unpackh2(xj1);
            wsum += wf.x + wf.y;
            ax += wf.x * x0.x + wf.y * x1.x;
            ay += wf.x * x0.y + wf.y * x1.y;
        }
    }
    float inv = 1.0f / wsum;
    unsigned int pk = (f2bf(ay * inv) << 16) | f2bf(ax * inv);
    sb[(size_t)idx * 64 + lane] = pk;
}

// route-sorted register accumulation, XCD-pinned per graph; uint2 loads
// (lane = (parity, c-pair)), parity merged by shfl_xor(32).
__global__ __launch_bounds__(256) void k_rnode(const int* __restrict__ rhist,
                                               const int* __restrict__ nid,
                                               const unsigned int* __restrict__ sb,
                                               float* __restrict__ part) {
    __shared__ float red[4][128];
    __shared__ int sseg[2];
    int bid = blockIdx.x;                    // [0, 2*NR*NCH) = 1280
    int xcd = bid & 7;
    int g = xcd >> 2;
    int rch = (xcd & 3) * (NR * NCH / 4) + (bid >> 3);   // [0, 640)
    int r = rch / NCH, ch = rch - r * NCH;
    if (threadIdx.x == 0) {
        int acc = 0;
        for (int rr = 0; rr < r; ++rr) acc += rhist[g * NR + rr];
        sseg[0] = acc;
        sseg[1] = rhist[g * NR + r];
    }
    __syncthreads();
    int seg0 = sseg[0], dgr = sseg[1];
    int csz = (dgr + NCH - 1) / NCH;
    int a = seg0 + ch * csz;
    int b = seg0 + dgr; { int bb = a + csz; if (bb < b) b = bb; }
    int ln = threadIdx.x >> 6;
    int lane = threadIdx.x & 63;
    int par = lane >> 5;                     // node parity within subwave
    int p = lane & 31;                       // c-pair (covers c=2p, 2p+1)
    const int* np = nid + g * NN;
    const unsigned int* sg = sb + (size_t)g * NN * 64;
    float sx0 = 0.f, sy0 = 0.f, sx1 = 0.f, sy1 = 0.f;
    for (int i = a + ln * 2 + par; i < b; i += 8) {
        int n = np[i];
        uint2 pk = *(const uint2*)&sg[(size_t)n * 64 + p * 2];
        sx0 += bf2f(pk.x & 0xffffu); sy0 += bf2f(pk.x >> 16);
        sx1 += bf2f(pk.y & 0xffffu); sy1 += bf2f(pk.y >> 16);
    }
    // merge parities within subwave
    sx0 += __shfl_xor(sx0, 32);
    sy0 += __shfl_xor(sy0, 32);
    sx1 += __shfl_xor(sx1, 32);
    sy1 += __shfl_xor(sy1, 32);
    if (par == 0) {
        red[ln][p * 4 + 0] = sx0;
        red[ln][p * 4 + 1] = sy0;
        red[ln][p * 4 + 2] = sx1;
        red[ln][p * 4 + 3] = sy1;
    }
    __syncthreads();
    int tid = threadIdx.x;
    if (tid < 128) {
        float s = red[0][tid] + red[1][tid] + red[2][tid] + red[3][tid];
        part[((g * NR + r) * NCH + ch) * 128 + tid] = s;
    }
}

// fused: chunk-partial reduce -> t row -> agg row (512) -> P[g,i,k]
__global__ __launch_bounds__(256) void k_head(const float* __restrict__ part,
                                              const int* __restrict__ rhist,
                                              const float* __restrict__ W,
                                              const float* __restrict__ bias,
                                              const float* __restrict__ Wh,
                                              float* __restrict__ P) {
    __shared__ float trow[128];
    __shared__ float aggL[512];
    __shared__ float scnt;
    int g = blockIdx.x / NR, i = blockIdx.x - g * NR;
    int tid = threadIdx.x;
    if (tid < 128) {
        const float* pp = part + ((g * NR + i) * NCH) * 128 + tid;
        float s = 0.f;
        for (int ch = 0; ch < NCH; ++ch) s += pp[ch * 128];
        trow[tid] = s;
    }
    if (tid == 0) scnt = (float)rhist[g * NR + i];
    __syncthreads();
    for (int hc = tid; hc < 512; hc += 256) {
        int h = hc >> 6;
        float acc = scnt * bias[hc];
        const float* tp = trow + h * 16;
        for (int f = 0; f < 16; ++f) acc += tp[f] * W[f * 512 + hc];
        aggL[hc] = acc;
    }
    __syncthreads();
    if (tid < 4 * NK) {
        int k = tid >> 2, qq = tid & 3;
        const float* wp = Wh + (size_t)(g * 512 + qq * 128) * 61 + k;
        const float* ap = aggL + qq * 128;
        float acc = 0.f;
        for (int d = 0; d < 128; ++d) acc += ap[d] * wp[d * 61];
        acc += __shfl_down(acc, 1);
        acc += __shfl_down(acc, 2);
        if (qq == 0) P[(g * NR + i) * NK + k] = acc;
    }
}

// factorized global softmax: logits = p1[i,k]+p2[j,k]+b[k]
__global__ __launch_bounds__(1024) void k_final(const float* __restrict__ P,
                                                const float* __restrict__ bh,
                                                float* __restrict__ out) {
    __shared__ float p1[NR * NK], p2[NR * NK];     // overwritten with e1,e2
    __shared__ float ak[NK], ck[NK], s1k[NK], s2k[NK];
    __shared__ float fk[NK];
    int tid = threadIdx.x;
    for (int i = tid; i < NR * NK; i += 1024) { p1[i] = P[i]; p2[i] = P[NR * NK + i]; }
    __syncthreads();
    if (tid < 2 * NK) {
        int k = (tid < NK) ? tid : tid - NK;
        float* pp = (tid < NK) ? p1 : p2;
        float a = -3.0e38f;
        for (int i = 0; i < NR; ++i) a = fmaxf(a, pp[i * NK + k]);
        float s = 0.f;
        for (int i = 0; i < NR; ++i) {
            float e = __expf(pp[i * NK + k] - a);
            pp[i * NK + k] = e;
            s += e;
        }
        if (tid < NK) { ak[k] = a; s1k[k] = s; }
        else          { ck[k] = a; s2k[k] = s; }
    }
    __syncthreads();
    if (tid == 0) {
        float M = -3.0e38f;
        float mk[NK];
        for (int k = 0; k < NK; ++k) {
            mk[k] = ak[k] + ck[k] + bh[k];
            M = fmaxf(M, mk[k]);
        }
        float den = 0.f;
        for (int k = 0; k < NK; ++k) den += s1k[k] * s2k[k] * __expf(mk[k] - M);
        float invden = 1.0f / den;
        for (int k = 0; k < NK; ++k) fk[k] = __expf(mk[k] - M) * invden;
    }
    __syncthreads();
    const int TOT = NR * NR * NK;
    for (int idx = tid; idx < TOT; idx += 1024) {
        int i = idx / (NR * NK);
        int r = idx - i * (NR * NK);
        int j = r / NK;
        int k = r - j * NK;
        out[idx] = p1[i * NK + k] * p2[j * NK + k] * fk[k];
    }
}

extern "C" void kernel_launch(void* const* d_in, const int* in_sizes, int n_in,
                              void* d_out, int out_size, void* d_ws, size_t ws_size,
                              hipStream_t stream) {
    const float* x1   = (const float*)d_in[0];
    const int*   ei1  = (const int*)d_in[1];
    const int*   rv1  = (const int*)d_in[3];
    const float* x2   = (const float*)d_in[5];
    const int*   ei2  = (const int*)d_in[6];
    const int*   rv2  = (const int*)d_in[8];
    const float* Wg   = (const float*)d_in[10];
    const float* asrc = (const float*)d_in[11];
    const float* adst = (const float*)d_in[12];
    const float* bias = (const float*)d_in[13];
    const float* Wh   = (const float*)d_in[14];
    const float* bh   = (const float*)d_in[15];
    float* out = (float*)d_out;
    float* ws  = (float*)d_ws;

    float* as_  = ws + OFF_AS;
    float* ad_  = ws + OFF_AD;
    float* P    = ws + OFF_P;
    float* part = ws + OFF_PART;
    unsigned int* sb = (unsigned int*)(ws + OFF_S);
    unsigned int* xh = (unsigned int*)(ws + OFF_XH);
    int* ibase  = (int*)(ws + OFF_INT);
    int* rhist  = ibase + IOFF_RHIST;
    int* bcur   = ibase + IOFF_BCUR;
    int* rcur   = ibase + IOFF_RCUR;
    int* start  = ibase + IOFF_START;
    int* deg    = ibase + IOFF_DEG;
    int* nid    = ibase + IOFF_NID;
    unsigned int* binned = (unsigned int*)(ibase + IOFF_BINNED);
    int* srcs   = ibase + IOFF_SRC;

    k_zero<<<1, 512, 0, stream>>>(rhist, srcs);
    k_front<<<2 * GAB + 2 * BPG2, 1024, 0, stream>>>(x1, x2, rv1, rv2, ei1, ei2,
                                                     Wg, asrc, adst, as_, ad_, xh,
                                                     rhist, bcur, binned);
    k_mid<<<2 * NB + 2 * NBLK, 256, 0, stream>>>(bcur, binned, rv1, rv2, rhist,
                                                 rcur, start, deg, srcs, nid);
    k_gather<<<2 * NN / 4, 256, 0, stream>>>(start, deg, srcs, as_, ad_, xh, sb);
    k_rnode<<<2 * NR * NCH, 256, 0, stream>>>(rhist, nid, sb, part);
    k_head<<<2 * NR, 256, 0, stream>>>(part, rhist, Wg, bias, Wh, P);
    k_final<<<1, 1024, 0, stream>>>(P, bh, out);
}